// Round 1
// baseline (602.693 us; speedup 1.0000x reference)
//
#include <hip/hip_runtime.h>
#include <hip/hip_bf16.h>

typedef float f32x4 __attribute__((ext_vector_type(4)));
typedef __bf16 bf16x8 __attribute__((ext_vector_type(8)));
typedef unsigned short u16x4 __attribute__((ext_vector_type(4)));

__device__ __forceinline__ unsigned short f2bf(float f) {
  unsigned u = __builtin_bit_cast(unsigned, f);
  u += 0x7FFFu + ((u >> 16) & 1u);
  return (unsigned short)(u >> 16);
}
__device__ __forceinline__ float bf2f(unsigned short h) {
  unsigned u = ((unsigned)h) << 16;
  return __builtin_bit_cast(float, u);
}

constexpr int BM = 128, BN = 128, BK = 32;
constexpr int LDSP = 40;  // padded LDS row (elements): 80B stride breaks bank conflicts

// C[m][n] = scale * sum_k A[m][k]*B[n][k]  (+ bias[n])
// A: [M][K] row-major (lda=K), B: [N][K] row-major (ldb=K). Batched via blockIdx.z.
// OUT_MODE: 0 = bf16 row-major [M][N]; 1 = bf16 transposed per-2048-row batch
//           (C[b][n][s], b=m>>11, s=m&2047, fixed seq len 2048); 2 = fp32 row-major.
template <bool IN_BF16, int OUT_MODE, bool HAS_BIAS>
__global__ __launch_bounds__(256) void gemm_abT(
    const void* __restrict__ Av, const void* __restrict__ Bv,
    const float* __restrict__ bias, float scale, void* __restrict__ Cv,
    int M, int N, int K, long sA, long sB, long sC) {
  __shared__ unsigned short As[BM * LDSP];
  __shared__ unsigned short Bs[BN * LDSP];

  const int t = threadIdx.x;
  const int rowBase = blockIdx.y * BM;
  const int colBase = blockIdx.x * BN;
  const int bz = blockIdx.z;

  // staging role: thread t loads 16 elements of row (t>>1), col-half (t&1)
  const int srow = t >> 1;
  const int scol = (t & 1) << 4;

  // wave/lane geometry: 4 waves in 2x2, each wave owns a 64x64 output tile
  const int lane = t & 63;
  const int w = t >> 6;
  const int wr = (w >> 1) << 6;
  const int wc = (w & 1) << 6;
  const int lr = lane & 15;
  const int lkb = (lane >> 4) << 3;  // k-element offset of this lane's frag slice

  f32x4 acc[4][4] = {{{0.f, 0.f, 0.f, 0.f}}};

  for (int k0 = 0; k0 < K; k0 += BK) {
    if constexpr (IN_BF16) {
      const unsigned short* Ag = (const unsigned short*)Av + sA * bz +
                                 (size_t)(rowBase + srow) * K + (k0 + scol);
      const unsigned short* Bg = (const unsigned short*)Bv + sB * bz +
                                 (size_t)(colBase + srow) * K + (k0 + scol);
      uint4 a0 = *(const uint4*)Ag;
      uint4 a1 = *(const uint4*)(Ag + 8);
      uint4 b0 = *(const uint4*)Bg;
      uint4 b1 = *(const uint4*)(Bg + 8);
      *(uint4*)&As[srow * LDSP + scol] = a0;
      *(uint4*)&As[srow * LDSP + scol + 8] = a1;
      *(uint4*)&Bs[srow * LDSP + scol] = b0;
      *(uint4*)&Bs[srow * LDSP + scol + 8] = b1;
    } else {
      const float* Ag = (const float*)Av + sA * bz +
                        (size_t)(rowBase + srow) * K + (k0 + scol);
      const float* Bg = (const float*)Bv + sB * bz +
                        (size_t)(colBase + srow) * K + (k0 + scol);
      float xa[16], xb[16];
      *(float4*)&xa[0] = *(const float4*)(Ag + 0);
      *(float4*)&xa[4] = *(const float4*)(Ag + 4);
      *(float4*)&xa[8] = *(const float4*)(Ag + 8);
      *(float4*)&xa[12] = *(const float4*)(Ag + 12);
      *(float4*)&xb[0] = *(const float4*)(Bg + 0);
      *(float4*)&xb[4] = *(const float4*)(Bg + 4);
      *(float4*)&xb[8] = *(const float4*)(Bg + 8);
      *(float4*)&xb[12] = *(const float4*)(Bg + 12);
      unsigned short ha[16], hb[16];
#pragma unroll
      for (int j = 0; j < 16; ++j) {
        ha[j] = f2bf(xa[j]);
        hb[j] = f2bf(xb[j]);
      }
      *(uint4*)&As[srow * LDSP + scol] = *(uint4*)&ha[0];
      *(uint4*)&As[srow * LDSP + scol + 8] = *(uint4*)&ha[8];
      *(uint4*)&Bs[srow * LDSP + scol] = *(uint4*)&hb[0];
      *(uint4*)&Bs[srow * LDSP + scol + 8] = *(uint4*)&hb[8];
    }
    __syncthreads();

    uint4 af[4], bg[4];
#pragma unroll
    for (int m = 0; m < 4; ++m)
      af[m] = *(const uint4*)&As[(wr + m * 16 + lr) * LDSP + lkb];
#pragma unroll
    for (int n = 0; n < 4; ++n)
      bg[n] = *(const uint4*)&Bs[(wc + n * 16 + lr) * LDSP + lkb];
#pragma unroll
    for (int m = 0; m < 4; ++m)
#pragma unroll
      for (int n = 0; n < 4; ++n)
        acc[m][n] = __builtin_amdgcn_mfma_f32_16x16x32_bf16(
            __builtin_bit_cast(bf16x8, af[m]), __builtin_bit_cast(bf16x8, bg[n]),
            acc[m][n], 0, 0, 0);
    __syncthreads();
  }

  // Epilogue. D lane mapping: col = lane&15, row = (lane>>4)*4 + r  [HW-verified]
#pragma unroll
  for (int n = 0; n < 4; ++n) {
    const int col = colBase + wc + n * 16 + lr;
    float bvv = 0.f;
    if constexpr (HAS_BIAS) bvv = bias[col];
#pragma unroll
    for (int m = 0; m < 4; ++m) {
      const int row0 = rowBase + wr + m * 16 + ((lane >> 4) << 2);
      f32x4 v = acc[m][n];
      if constexpr (OUT_MODE == 0) {
        unsigned short* C = (unsigned short*)Cv + sC * bz;
#pragma unroll
        for (int r = 0; r < 4; ++r)
          C[(size_t)(row0 + r) * N + col] = f2bf(v[r] * scale + bvv);
      } else if constexpr (OUT_MODE == 1) {
        unsigned short* C = (unsigned short*)Cv;
        const int b = row0 >> 11, s = row0 & 2047;
        u16x4 pk;
#pragma unroll
        for (int r = 0; r < 4; ++r) pk[r] = f2bf(v[r] * scale + bvv);
        *(u16x4*)&C[((size_t)b * N + col) * 2048 + s] = pk;
      } else {
        float* C = (float*)Cv + sC * bz;
#pragma unroll
        for (int r = 0; r < 4; ++r)
          C[(size_t)(row0 + r) * N + col] = v[r] * scale + bvv;
      }
    }
  }
}

// In-place softmax over rows of 2048 bf16 scores. One block (256 thr) per row.
__global__ __launch_bounds__(256) void softmax_inplace(unsigned short* __restrict__ S) {
  const size_t row = blockIdx.x;
  unsigned short* p = S + row * 2048;
  const int t = threadIdx.x;
  const int lane = t & 63, wid = t >> 6;

  uint4 x = ((const uint4*)p)[t];
  unsigned short* hs = (unsigned short*)&x;
  float f[8];
#pragma unroll
  for (int j = 0; j < 8; ++j) f[j] = bf2f(hs[j]);

  float mx = f[0];
#pragma unroll
  for (int j = 1; j < 8; ++j) mx = fmaxf(mx, f[j]);
#pragma unroll
  for (int d = 1; d < 64; d <<= 1) mx = fmaxf(mx, __shfl_xor(mx, d));
  __shared__ float redm[4];
  if (lane == 0) redm[wid] = mx;
  __syncthreads();
  mx = fmaxf(fmaxf(redm[0], redm[1]), fmaxf(redm[2], redm[3]));

  float e[8], s = 0.f;
#pragma unroll
  for (int j = 0; j < 8; ++j) {
    e[j] = __expf(f[j] - mx);
    s += e[j];
  }
#pragma unroll
  for (int d = 1; d < 64; d <<= 1) s += __shfl_xor(s, d);
  __shared__ float reds[4];
  if (lane == 0) reds[wid] = s;
  __syncthreads();
  s = reds[0] + reds[1] + reds[2] + reds[3];
  const float inv = 1.f / s;

#pragma unroll
  for (int j = 0; j < 8; ++j) hs[j] = f2bf(e[j] * inv);
  ((uint4*)p)[t] = x;
}

extern "C" void kernel_launch(void* const* d_in, const int* in_sizes, int n_in,
                              void* d_out, int out_size, void* d_ws, size_t ws_size,
                              hipStream_t stream) {
  const float* q_embd = (const float*)d_in[0];
  const float* k_embd = (const float*)d_in[1];
  const float* v_embd = (const float*)d_in[2];
  const float* Wq = (const float*)d_in[3];
  const float* bq = (const float*)d_in[4];
  const float* Wk = (const float*)d_in[5];
  const float* bk = (const float*)d_in[6];
  const float* Wv = (const float*)d_in[7];
  const float* bv = (const float*)d_in[8];

  constexpr int B = 8, QL = 2048, KL = 2048, D = 1024;

  unsigned short* qb = (unsigned short*)d_ws;                 // [B*QL][D] bf16
  unsigned short* kb = qb + (size_t)B * QL * D;               // [B*KL][D] bf16
  unsigned short* vT = kb + (size_t)B * KL * D;               // [B][D][KL] bf16
  unsigned short* Sb = vT + (size_t)B * KL * D;               // [B][QL][KL] bf16

  dim3 blk(256);

  // QKV projections: x @ W^T + b
  gemm_abT<false, 0, true><<<dim3(D / BN, (B * QL) / BM, 1), blk, 0, stream>>>(
      q_embd, Wq, bq, 1.0f, qb, B * QL, D, D, 0L, 0L, 0L);
  gemm_abT<false, 0, true><<<dim3(D / BN, (B * KL) / BM, 1), blk, 0, stream>>>(
      k_embd, Wk, bk, 1.0f, kb, B * KL, D, D, 0L, 0L, 0L);
  gemm_abT<false, 1, true><<<dim3(D / BN, (B * KL) / BM, 1), blk, 0, stream>>>(
      v_embd, Wv, bv, 1.0f, vT, B * KL, D, D, 0L, 0L, 0L);

  // S = (Q @ K^T) / sqrt(D)  per batch
  gemm_abT<true, 0, false><<<dim3(KL / BN, QL / BM, B), blk, 0, stream>>>(
      qb, kb, nullptr, 0.03125f, Sb, QL, KL, D,
      (long)QL * D, (long)KL * D, (long)QL * KL);

  // P = softmax(S) row-wise, in place
  softmax_inplace<<<dim3(B * QL), blk, 0, stream>>>(Sb);

  // out = P @ V  (V stored transposed, so this is P @ vT^T)
  gemm_abT<true, 2, false><<<dim3(D / BN, QL / BM, B), blk, 0, stream>>>(
      Sb, vT, nullptr, 1.0f, d_out, QL, D, KL,
      (long)QL * KL, (long)D * KL, (long)QL * D);
}

// Round 2
// 490.784 us; speedup vs baseline: 1.2280x; 1.2280x over previous
//
#include <hip/hip_runtime.h>
#include <hip/hip_bf16.h>

typedef float f32x4 __attribute__((ext_vector_type(4)));
typedef __bf16 bf16x8 __attribute__((ext_vector_type(8)));
typedef unsigned short u16x4 __attribute__((ext_vector_type(4)));

__device__ __forceinline__ unsigned short f2bf(float f) {
  unsigned u = __builtin_bit_cast(unsigned, f);
  u += 0x7FFFu + ((u >> 16) & 1u);
  return (unsigned short)(u >> 16);
}
__device__ __forceinline__ float bf2f(unsigned short h) {
  unsigned u = ((unsigned)h) << 16;
  return __builtin_bit_cast(float, u);
}

__device__ __forceinline__ void gload_lds16(const void* g, void* l) {
  __builtin_amdgcn_global_load_lds(
      (const __attribute__((address_space(1))) void*)g,
      (__attribute__((address_space(3))) void*)l, 16, 0, 0);
}

constexpr int TM = 128, TN = 128, TK = 32;

// C[m][n] = scale * sum_k A[m][k]*B[n][k] (+ bias[n]). A:[M][K], B:[N][K] bf16.
// m97 structure: global_load_lds width-16 staging, linear LDS, 2-barrier loop.
// OUT_MODE: 0 = bf16 row-major [M][N]; 1 = bf16 transposed (C[b][n][s], seq 2048);
//           2 = fp32 row-major.
template <int OUT_MODE, bool HAS_BIAS>
__global__ __launch_bounds__(256) void gemm_bf16(
    const unsigned short* __restrict__ A, const unsigned short* __restrict__ B,
    const float* __restrict__ bias, float scale, void* __restrict__ Cv,
    int N, int K, long sA, long sB, long sC) {
  __shared__ unsigned short As[TM * TK];
  __shared__ unsigned short Bs[TN * TK];

  const int t = threadIdx.x;
  const int lane = t & 63;
  const int w = t >> 6;
  const int rowBase = blockIdx.y * TM;
  const int colBase = blockIdx.x * TN;
  const int bz = blockIdx.z;

  // gload_lds geometry: wave w stages 16-row stripe; lane l -> row l>>2, 8-elem
  // chunk (l&3)*8. LDS dest is wave-uniform base + lane*16 (linear order).
  const int strow = lane >> 2;
  const int stcol = (lane & 3) << 3;

  const unsigned short* Ab = A + sA * bz;
  const unsigned short* Bb = B + sB * bz;

  // MFMA fragment geometry (16x16x32): lane -> row lane&15, k-slice (lane>>4)*8
  const int lr = lane & 15;
  const int lkb = (lane >> 4) << 3;
  const int wr = (w >> 1) << 6;  // wave's 64x64 quadrant
  const int wc = (w & 1) << 6;

  f32x4 acc[4][4] = {{{0.f, 0.f, 0.f, 0.f}}};

  for (int k0 = 0; k0 < K; k0 += TK) {
#pragma unroll
    for (int s = 0; s < 2; ++s) {
      const int r0 = s * 64 + w * 16;
      gload_lds16(Ab + (size_t)(rowBase + r0 + strow) * K + k0 + stcol,
                  &As[r0 * TK]);
      gload_lds16(Bb + (size_t)(colBase + r0 + strow) * K + k0 + stcol,
                  &Bs[r0 * TK]);
    }
    __syncthreads();

    uint4 af[4], bg[4];
#pragma unroll
    for (int m = 0; m < 4; ++m)
      af[m] = *(const uint4*)&As[(wr + m * 16 + lr) * TK + lkb];
#pragma unroll
    for (int n = 0; n < 4; ++n)
      bg[n] = *(const uint4*)&Bs[(wc + n * 16 + lr) * TK + lkb];
#pragma unroll
    for (int m = 0; m < 4; ++m)
#pragma unroll
      for (int n = 0; n < 4; ++n)
        acc[m][n] = __builtin_amdgcn_mfma_f32_16x16x32_bf16(
            __builtin_bit_cast(bf16x8, af[m]), __builtin_bit_cast(bf16x8, bg[n]),
            acc[m][n], 0, 0, 0);
    __syncthreads();
  }

  // Epilogue. D lane mapping: col = lane&15, row = (lane>>4)*4 + r  [HW-verified]
#pragma unroll
  for (int n = 0; n < 4; ++n) {
    const int col = colBase + wc + n * 16 + lr;
    float bvv = 0.f;
    if constexpr (HAS_BIAS) bvv = bias[col];
#pragma unroll
    for (int m = 0; m < 4; ++m) {
      const int row0 = rowBase + wr + m * 16 + ((lane >> 4) << 2);
      f32x4 v = acc[m][n];
      if constexpr (OUT_MODE == 0) {
        unsigned short* C = (unsigned short*)Cv + sC * bz;
#pragma unroll
        for (int r = 0; r < 4; ++r)
          C[(size_t)(row0 + r) * N + col] = f2bf(v[r] * scale + bvv);
      } else if constexpr (OUT_MODE == 1) {
        unsigned short* C = (unsigned short*)Cv;
        const int b = row0 >> 11, s = row0 & 2047;
        u16x4 pk;
#pragma unroll
        for (int r = 0; r < 4; ++r) pk[r] = f2bf(v[r] * scale + bvv);
        *(u16x4*)&C[((size_t)b * N + col) * 2048 + s] = pk;
      } else {
        float* C = (float*)Cv + sC * bz;
#pragma unroll
        for (int r = 0; r < 4; ++r)
          C[(size_t)(row0 + r) * N + col] = v[r] * scale + bvv;
      }
    }
  }
}

// fp32 -> bf16 (RNE), 8 elems/thread/iter, grid-stride.
__global__ __launch_bounds__(256) void f32_to_bf16(
    const float* __restrict__ in, unsigned short* __restrict__ out, int n8) {
  int i = blockIdx.x * 256 + threadIdx.x;
  const int stride = gridDim.x * 256;
  for (; i < n8; i += stride) {
    float4 a = ((const float4*)in)[2 * i];
    float4 b = ((const float4*)in)[2 * i + 1];
    unsigned short h[8];
    h[0] = f2bf(a.x); h[1] = f2bf(a.y); h[2] = f2bf(a.z); h[3] = f2bf(a.w);
    h[4] = f2bf(b.x); h[5] = f2bf(b.y); h[6] = f2bf(b.z); h[7] = f2bf(b.w);
    ((uint4*)out)[i] = *(uint4*)h;
  }
}

// In-place softmax over rows of 2048 bf16 scores. One block (256 thr) per row.
__global__ __launch_bounds__(256) void softmax_inplace(unsigned short* __restrict__ S) {
  const size_t row = blockIdx.x;
  unsigned short* p = S + row * 2048;
  const int t = threadIdx.x;
  const int lane = t & 63, wid = t >> 6;

  uint4 x = ((const uint4*)p)[t];
  unsigned short* hs = (unsigned short*)&x;
  float f[8];
#pragma unroll
  for (int j = 0; j < 8; ++j) f[j] = bf2f(hs[j]);

  float mx = f[0];
#pragma unroll
  for (int j = 1; j < 8; ++j) mx = fmaxf(mx, f[j]);
#pragma unroll
  for (int d = 1; d < 64; d <<= 1) mx = fmaxf(mx, __shfl_xor(mx, d));
  __shared__ float redm[4];
  if (lane == 0) redm[wid] = mx;
  __syncthreads();
  mx = fmaxf(fmaxf(redm[0], redm[1]), fmaxf(redm[2], redm[3]));

  float e[8], s = 0.f;
#pragma unroll
  for (int j = 0; j < 8; ++j) {
    e[j] = __expf(f[j] - mx);
    s += e[j];
  }
#pragma unroll
  for (int d = 1; d < 64; d <<= 1) s += __shfl_xor(s, d);
  __shared__ float reds[4];
  if (lane == 0) reds[wid] = s;
  __syncthreads();
  s = reds[0] + reds[1] + reds[2] + reds[3];
  const float inv = 1.f / s;

#pragma unroll
  for (int j = 0; j < 8; ++j) hs[j] = f2bf(e[j] * inv);
  ((uint4*)p)[t] = x;
}

extern "C" void kernel_launch(void* const* d_in, const int* in_sizes, int n_in,
                              void* d_out, int out_size, void* d_ws, size_t ws_size,
                              hipStream_t stream) {
  const float* q_embd = (const float*)d_in[0];
  const float* k_embd = (const float*)d_in[1];
  const float* v_embd = (const float*)d_in[2];
  const float* Wq = (const float*)d_in[3];
  const float* bq = (const float*)d_in[4];
  const float* Wk = (const float*)d_in[5];
  const float* bk = (const float*)d_in[6];
  const float* Wv = (const float*)d_in[7];
  const float* bv = (const float*)d_in[8];

  constexpr int B = 8, QL = 2048, KL = 2048, D = 1024;
  constexpr size_t NE = (size_t)B * QL * D;  // 16.78M elems per embedding

  // ws layout (exactly 160 MiB, proven sufficient in round 1):
  unsigned short* qb = (unsigned short*)d_ws;  // [B*QL][D]
  unsigned short* kb = qb + NE;                // [B*KL][D]
  unsigned short* vT = kb + NE;                // [B][D][KL]
  unsigned short* Sb = vT + NE;                // [B][QL][KL] (64 MiB)
  // conversion staging lives inside Sb's region (dead until QK^T):
  unsigned short* Xe = Sb;       // converted embedding, 32 MiB
  unsigned short* Wb = Sb + NE;  // converted weight, 2 MiB

  dim3 blk(256);
  const dim3 gconvE(2048), gconvW(512);
  const dim3 gproj(D / TN, (B * QL) / TM, 1);

  // --- Q projection ---
  f32_to_bf16<<<gconvE, blk, 0, stream>>>(q_embd, Xe, (int)(NE / 8));
  f32_to_bf16<<<gconvW, blk, 0, stream>>>(Wq, Wb, D * D / 8);
  gemm_bf16<0, true><<<gproj, blk, 0, stream>>>(Xe, Wb, bq, 1.0f, qb, D, D, 0L, 0L, 0L);

  // --- K projection ---
  f32_to_bf16<<<gconvE, blk, 0, stream>>>(k_embd, Xe, (int)(NE / 8));
  f32_to_bf16<<<gconvW, blk, 0, stream>>>(Wk, Wb, D * D / 8);
  gemm_bf16<0, true><<<gproj, blk, 0, stream>>>(Xe, Wb, bk, 1.0f, kb, D, D, 0L, 0L, 0L);

  // --- V projection (transposed output) ---
  f32_to_bf16<<<gconvE, blk, 0, stream>>>(v_embd, Xe, (int)(NE / 8));
  f32_to_bf16<<<gconvW, blk, 0, stream>>>(Wv, Wb, D * D / 8);
  gemm_bf16<1, true><<<gproj, blk, 0, stream>>>(Xe, Wb, bv, 1.0f, vT, D, D, 0L, 0L, 0L);

  // --- S = (Q @ K^T) / sqrt(D), per batch (overwrites Xe/Wb region) ---
  gemm_bf16<0, false><<<dim3(KL / TN, QL / TM, B), blk, 0, stream>>>(
      qb, kb, nullptr, 0.03125f, Sb, KL, D, (long)QL * D, (long)KL * D,
      (long)QL * KL);

  // --- P = softmax(S), in place ---
  softmax_inplace<<<dim3(B * QL), blk, 0, stream>>>(Sb);

  // --- out = P @ V (V stored transposed) ---
  gemm_bf16<2, false><<<dim3(D / TN, QL / TM, B), blk, 0, stream>>>(
      Sb, vT, nullptr, 1.0f, d_out, D, KL, (long)QL * KL, (long)D * KL,
      (long)QL * D);
}

// Round 3
// 480.011 us; speedup vs baseline: 1.2556x; 1.0224x over previous
//
#include <hip/hip_runtime.h>
#include <hip/hip_bf16.h>

typedef float f32x4 __attribute__((ext_vector_type(4)));
typedef __bf16 bf16x8 __attribute__((ext_vector_type(8)));
typedef unsigned short u16x4 __attribute__((ext_vector_type(4)));

__device__ __forceinline__ unsigned short f2bf(float f) {
  unsigned u = __builtin_bit_cast(unsigned, f);
  u += 0x7FFFu + ((u >> 16) & 1u);
  return (unsigned short)(u >> 16);
}
__device__ __forceinline__ float bf2f(unsigned short h) {
  unsigned u = ((unsigned)h) << 16;
  return __builtin_bit_cast(float, u);
}

__device__ __forceinline__ void gload_lds16(const void* g, void* l) {
  __builtin_amdgcn_global_load_lds(
      (const __attribute__((address_space(1))) void*)g,
      (__attribute__((address_space(3))) void*)l, 16, 0, 0);
}

// ---------------- 256x256 8-phase bf16 GEMM (m201-style template) -----------
// C[m][n] = scale * sum_k A[m][k]*B[n][k] (+ bias[n]). A:[M][K], B:[N][K] bf16.
// 512 thr = 8 waves (2Mx4N), BK=64, LDS 128KiB double-buffered, chunk-XOR
// swizzle (slot = g ^ (row&7)) with inverse-swizzled gload source, Gray-code
// 4-phase K-tiles, counted vmcnt(4), setprio around MFMA, XCD block swizzle.
constexpr int BM = 256, BN = 256, BK = 64;

#define BAR() __builtin_amdgcn_s_barrier()
#define LGKM0()                                     \
  do {                                              \
    asm volatile("s_waitcnt lgkmcnt(0)" ::: "memory"); \
    __builtin_amdgcn_sched_barrier(0);              \
  } while (0)
#define VMW(N) asm volatile("s_waitcnt vmcnt(" #N ")" ::: "memory")
#define PRIO(x) __builtin_amdgcn_s_setprio(x)

#define MM(a_, b_, c_)                                                        \
  c_ = __builtin_amdgcn_mfma_f32_16x16x32_bf16(                               \
      __builtin_bit_cast(bf16x8, a_), __builtin_bit_cast(bf16x8, b_), c_, 0, 0, 0)

template <int OUT_MODE, bool HAS_BIAS>
__global__ __launch_bounds__(512, 2) void gemm256(
    const unsigned short* __restrict__ A, const unsigned short* __restrict__ B,
    const float* __restrict__ bias, float scale, void* __restrict__ Cv,
    int N, int K, long sA, long sB, long sC, int gx, int gy) {
  __shared__ char sm[131072];  // A: [0,64K) = dbuf*32K + half*16K; B: +64K same

  const int nwg = gridDim.x;
  int id = blockIdx.x;
  id = (id & 7) * (nwg >> 3) + (id >> 3);  // XCD swizzle (nwg % 8 == 0)
  const int bx = id % gx;
  const int by = (id / gx) % gy;
  const int bz = id / (gx * gy);

  const int t = threadIdx.x;
  const int lane = t & 63;
  const int w = t >> 6;   // 0..7
  const int wm = w >> 2;  // 0..1
  const int wn = w & 3;   // 0..3

  const int rowBase = by * BM;
  const int colBase = bx * BN;
  const unsigned short* Ab = A + sA * bz;
  const unsigned short* Bb = B + sB * bz;
  const int NT = K >> 6;  // K-tiles of 64 (even, >= 2)

  // staging: per half-tile (128 rows x 64 cols), wave w issue j covers rows
  // [(w+8j)*8, +8); lane l -> row +(l>>3), slot l&7; source chunk inverse-swz.
  const int srl = lane >> 3;
  const int schunk = (lane & 7) ^ srl;

#define STAGE_A(tt, h, d)                                                     \
  do {                                                                        \
    int _kt = (tt); if (_kt > NT - 1) _kt = NT - 1;                           \
    const int _k0 = _kt << 6;                                                 \
    _Pragma("unroll") for (int _j = 0; _j < 2; ++_j) {                        \
      const int _r = (w + 8 * _j) * 8 + srl;                                  \
      gload_lds16(Ab + (size_t)(rowBase + (h) * 128 + _r) * K + _k0 + schunk * 8, \
                  sm + (d) * 32768 + (h) * 16384 + (w + 8 * _j) * 1024);      \
    }                                                                         \
  } while (0)
#define STAGE_B(tt, h, d)                                                     \
  do {                                                                        \
    int _kt = (tt); if (_kt > NT - 1) _kt = NT - 1;                           \
    const int _k0 = _kt << 6;                                                 \
    _Pragma("unroll") for (int _j = 0; _j < 2; ++_j) {                        \
      const int _r = (w + 8 * _j) * 8 + srl;                                  \
      gload_lds16(Bb + (size_t)(colBase + (h) * 128 + _r) * K + _k0 + schunk * 8, \
                  sm + 65536 + (d) * 32768 + (h) * 16384 + (w + 8 * _j) * 1024); \
    }                                                                         \
  } while (0)

  // fragment reads: row_local*128 + (g ^ (row&7))*16; row&7 == lr&7 here.
  const int lr = lane & 15;
  const int g0 = lane >> 4;
  const int sw0 = (g0 ^ (lr & 7)) << 4;
  const int sw1 = ((g0 + 4) ^ (lr & 7)) << 4;
  const int aoff0 = wm * 16384 + lr * 128 + sw0;
  const int aoff1 = wm * 16384 + lr * 128 + sw1;
  const int boff0 = (wn >> 1) * 16384 + (wn & 1) * 8192 + lr * 128 + sw0;
  const int boff1 = (wn >> 1) * 16384 + (wn & 1) * 8192 + lr * 128 + sw1;

  uint4 AL[2][4][2], AH[2][4][2], BL[2][2][2], BH[2][2][2];
  f32x4 acc[8][4];
#pragma unroll
  for (int m = 0; m < 8; ++m)
#pragma unroll
    for (int n = 0; n < 4; ++n) acc[m][n] = (f32x4){0.f, 0.f, 0.f, 0.f};

#define READ_AL(bk, d)                                                        \
  do {                                                                        \
    _Pragma("unroll") for (int f = 0; f < 4; ++f) {                           \
      AL[bk][f][0] = *(const uint4*)(sm + (d) * 32768 + (f * 16) * 128 + aoff0); \
      AL[bk][f][1] = *(const uint4*)(sm + (d) * 32768 + (f * 16) * 128 + aoff1); \
    }                                                                         \
  } while (0)
#define READ_AH(bk, d)                                                        \
  do {                                                                        \
    _Pragma("unroll") for (int f = 0; f < 4; ++f) {                           \
      AH[bk][f][0] = *(const uint4*)(sm + (d) * 32768 + (64 + f * 16) * 128 + aoff0); \
      AH[bk][f][1] = *(const uint4*)(sm + (d) * 32768 + (64 + f * 16) * 128 + aoff1); \
    }                                                                         \
  } while (0)
#define READ_BL(bk, d)                                                        \
  do {                                                                        \
    _Pragma("unroll") for (int f = 0; f < 2; ++f) {                           \
      BL[bk][f][0] = *(const uint4*)(sm + 65536 + (d) * 32768 + (f * 16) * 128 + boff0); \
      BL[bk][f][1] = *(const uint4*)(sm + 65536 + (d) * 32768 + (f * 16) * 128 + boff1); \
    }                                                                         \
  } while (0)
#define READ_BH(bk, d)                                                        \
  do {                                                                        \
    _Pragma("unroll") for (int f = 0; f < 2; ++f) {                           \
      BH[bk][f][0] = *(const uint4*)(sm + 65536 + (d) * 32768 + (32 + f * 16) * 128 + boff0); \
      BH[bk][f][1] = *(const uint4*)(sm + 65536 + (d) * 32768 + (32 + f * 16) * 128 + boff1); \
    }                                                                         \
  } while (0)

#define MFMA_PH(Aarr, bk, mh, Barr, nh)                                       \
  do {                                                                        \
    _Pragma("unroll") for (int kk = 0; kk < 2; ++kk)                          \
        _Pragma("unroll") for (int mf = 0; mf < 4; ++mf)                      \
            _Pragma("unroll") for (int nf = 0; nf < 2; ++nf)                  \
                MM(Aarr[bk][mf][kk], Barr[bk][nf][kk],                        \
                   acc[(mh) * 4 + mf][(nh) * 2 + nf]);                        \
  } while (0)

  // Per-tile 4 phases (Gray order m0n0, m0n1, m1n1, m1n0). Stage slots chosen
  // so each dest region is >=1 barrier past its last ds_read; vmcnt(4) at ph3
  // end guarantees tile t+1 fully landed before ph4's reads of it.
#define TILE(t_, d_, CUR, NXT)                                                \
  do {                                                                        \
    /* ph1 */ READ_BH(CUR, d_);                                               \
    STAGE_A((t_) + 1, 1, (d_) ^ 1);                                           \
    BAR(); LGKM0();                                                           \
    PRIO(1); MFMA_PH(AL, CUR, 0, BL, 0); PRIO(0);                             \
    BAR();                                                                    \
    /* ph2 */ READ_AH(CUR, d_);                                               \
    STAGE_B((t_) + 2, 0, d_);                                                 \
    BAR(); LGKM0();                                                           \
    PRIO(1); MFMA_PH(AL, CUR, 0, BH, 1); PRIO(0);                             \
    BAR();                                                                    \
    /* ph3 */ STAGE_B((t_) + 2, 1, d_);                                       \
    BAR();                                                                    \
    PRIO(1); MFMA_PH(AH, CUR, 1, BH, 1); PRIO(0);                             \
    VMW(4);                                                                   \
    BAR();                                                                    \
    /* ph4 */ READ_BL(NXT, (d_) ^ 1); READ_AL(NXT, (d_) ^ 1);                 \
    STAGE_A((t_) + 2, 0, d_);                                                 \
    BAR(); LGKM0();                                                           \
    PRIO(1); MFMA_PH(AH, CUR, 1, BL, 0); PRIO(0);                             \
    BAR();                                                                    \
  } while (0)

  // prologue: stage B0(0),B1(0),A0(0),A1(0),B0(1),B1(1),A0(1); tile0 landed.
  STAGE_B(0, 0, 0); STAGE_B(0, 1, 0); STAGE_A(0, 0, 0); STAGE_A(0, 1, 0);
  STAGE_B(1, 0, 1); STAGE_B(1, 1, 1); STAGE_A(1, 0, 1);
  VMW(6);
  BAR();
  READ_BL(0, 0); READ_AL(0, 0);

  for (int i = 0; i < (NT >> 1); ++i) {
    const int t0 = 2 * i;
    TILE(t0, 0, 0, 1);
    TILE(t0 + 1, 1, 1, 0);
  }
  VMW(0);  // drain stray prefetches before workgroup teardown

  // Epilogue. D lane mapping: col = lane&15, row = (lane>>4)*4 + r.
#pragma unroll
  for (int n = 0; n < 4; ++n) {
    const int col = colBase + wn * 64 + n * 16 + lr;
    float bvv = 0.f;
    if constexpr (HAS_BIAS) bvv = bias[col];
#pragma unroll
    for (int m = 0; m < 8; ++m) {
      const int row0 = rowBase + wm * 128 + m * 16 + g0 * 4;
      f32x4 v = acc[m][n];
      if constexpr (OUT_MODE == 0) {
        unsigned short* C = (unsigned short*)Cv + sC * bz;
#pragma unroll
        for (int r = 0; r < 4; ++r)
          C[(size_t)(row0 + r) * N + col] = f2bf(v[r] * scale + bvv);
      } else if constexpr (OUT_MODE == 1) {
        unsigned short* C = (unsigned short*)Cv;
        const int b = row0 >> 11, s = row0 & 2047;
        u16x4 pk;
#pragma unroll
        for (int r = 0; r < 4; ++r) pk[r] = f2bf(v[r] * scale + bvv);
        *(u16x4*)&C[((size_t)b * N + col) * 2048 + s] = pk;
      } else {
        float* C = (float*)Cv + sC * bz;
#pragma unroll
        for (int r = 0; r < 4; ++r)
          C[(size_t)(row0 + r) * N + col] = v[r] * scale + bvv;
      }
    }
  }
}

// fp32 -> bf16 (RNE), 8 elems/thread/iter, grid-stride.
__global__ __launch_bounds__(256) void f32_to_bf16(
    const float* __restrict__ in, unsigned short* __restrict__ out, int n8) {
  int i = blockIdx.x * 256 + threadIdx.x;
  const int stride = gridDim.x * 256;
  for (; i < n8; i += stride) {
    float4 a = ((const float4*)in)[2 * i];
    float4 b = ((const float4*)in)[2 * i + 1];
    unsigned short h[8];
    h[0] = f2bf(a.x); h[1] = f2bf(a.y); h[2] = f2bf(a.z); h[3] = f2bf(a.w);
    h[4] = f2bf(b.x); h[5] = f2bf(b.y); h[6] = f2bf(b.z); h[7] = f2bf(b.w);
    ((uint4*)out)[i] = *(uint4*)h;
  }
}

// In-place softmax over rows of 2048 bf16 scores. One block (256 thr) per row.
__global__ __launch_bounds__(256) void softmax_inplace(unsigned short* __restrict__ S) {
  const size_t row = blockIdx.x;
  unsigned short* p = S + row * 2048;
  const int t = threadIdx.x;
  const int lane = t & 63, wid = t >> 6;

  uint4 x = ((const uint4*)p)[t];
  unsigned short* hs = (unsigned short*)&x;
  float f[8];
#pragma unroll
  for (int j = 0; j < 8; ++j) f[j] = bf2f(hs[j]);

  float mx = f[0];
#pragma unroll
  for (int j = 1; j < 8; ++j) mx = fmaxf(mx, f[j]);
#pragma unroll
  for (int d = 1; d < 64; d <<= 1) mx = fmaxf(mx, __shfl_xor(mx, d));
  __shared__ float redm[4];
  if (lane == 0) redm[wid] = mx;
  __syncthreads();
  mx = fmaxf(fmaxf(redm[0], redm[1]), fmaxf(redm[2], redm[3]));

  float e[8], s = 0.f;
#pragma unroll
  for (int j = 0; j < 8; ++j) {
    e[j] = __expf(f[j] - mx);
    s += e[j];
  }
#pragma unroll
  for (int d = 1; d < 64; d <<= 1) s += __shfl_xor(s, d);
  __shared__ float reds[4];
  if (lane == 0) reds[wid] = s;
  __syncthreads();
  s = reds[0] + reds[1] + reds[2] + reds[3];
  const float inv = 1.f / s;

#pragma unroll
  for (int j = 0; j < 8; ++j) hs[j] = f2bf(e[j] * inv);
  ((uint4*)p)[t] = x;
}

extern "C" void kernel_launch(void* const* d_in, const int* in_sizes, int n_in,
                              void* d_out, int out_size, void* d_ws, size_t ws_size,
                              hipStream_t stream) {
  const float* q_embd = (const float*)d_in[0];
  const float* k_embd = (const float*)d_in[1];
  const float* v_embd = (const float*)d_in[2];
  const float* Wq = (const float*)d_in[3];
  const float* bq = (const float*)d_in[4];
  const float* Wk = (const float*)d_in[5];
  const float* bk = (const float*)d_in[6];
  const float* Wv = (const float*)d_in[7];
  const float* bv = (const float*)d_in[8];

  constexpr int B = 8, QL = 2048, KL = 2048, D = 1024;
  constexpr size_t NE = (size_t)B * QL * D;

  unsigned short* qb = (unsigned short*)d_ws;  // [B*QL][D]
  unsigned short* kb = qb + NE;                // [B*KL][D]
  unsigned short* vT = kb + NE;                // [B][D][KL]
  unsigned short* Sb = vT + NE;                // [B][QL][KL] (64 MiB)
  unsigned short* Xe = Sb;                     // conv staging (dead until QK^T)
  unsigned short* Wb = Sb + NE;

  dim3 blk256(256), blk512(512);
  const dim3 gconvE(2048), gconvW(512);
  // proj grid: gx=D/256=4, gy=(B*QL)/256=64 -> 256 blocks
  const dim3 gproj(4 * 64);

  // --- Q projection ---
  f32_to_bf16<<<gconvE, blk256, 0, stream>>>(q_embd, Xe, (int)(NE / 8));
  f32_to_bf16<<<gconvW, blk256, 0, stream>>>(Wq, Wb, D * D / 8);
  gemm256<0, true><<<gproj, blk512, 0, stream>>>(Xe, Wb, bq, 1.0f, qb, D, D,
                                                 0L, 0L, 0L, 4, 64);
  // --- K projection ---
  f32_to_bf16<<<gconvE, blk256, 0, stream>>>(k_embd, Xe, (int)(NE / 8));
  f32_to_bf16<<<gconvW, blk256, 0, stream>>>(Wk, Wb, D * D / 8);
  gemm256<0, true><<<gproj, blk512, 0, stream>>>(Xe, Wb, bk, 1.0f, kb, D, D,
                                                 0L, 0L, 0L, 4, 64);
  // --- V projection (transposed output) ---
  f32_to_bf16<<<gconvE, blk256, 0, stream>>>(v_embd, Xe, (int)(NE / 8));
  f32_to_bf16<<<gconvW, blk256, 0, stream>>>(Wv, Wb, D * D / 8);
  gemm256<1, true><<<gproj, blk512, 0, stream>>>(Xe, Wb, bv, 1.0f, vT, D, D,
                                                 0L, 0L, 0L, 4, 64);

  // --- S = (Q @ K^T)/sqrt(D): gx=8, gy=8, gz=8 -> 512 blocks ---
  gemm256<0, false><<<dim3(512), blk512, 0, stream>>>(
      qb, kb, nullptr, 0.03125f, Sb, KL, D, (long)QL * D, (long)KL * D,
      (long)QL * KL, 8, 8);

  // --- P = softmax(S), in place ---
  softmax_inplace<<<dim3(B * QL), blk256, 0, stream>>>(Sb);

  // --- out = P @ V: gx=4, gy=8, gz=8 -> 256 blocks ---
  gemm256<2, false><<<dim3(256), blk512, 0, stream>>>(
      Sb, vT, nullptr, 1.0f, d_out, D, KL, (long)QL * KL, (long)D * KL,
      (long)QL * D, 4, 8);
}

// Round 4
// 418.084 us; speedup vs baseline: 1.4416x; 1.1481x over previous
//
#include <hip/hip_runtime.h>
#include <hip/hip_bf16.h>

typedef float f32x4 __attribute__((ext_vector_type(4)));
typedef __bf16 bf16x8 __attribute__((ext_vector_type(8)));
typedef unsigned short u16x4 __attribute__((ext_vector_type(4)));

__device__ __forceinline__ unsigned short f2bf(float f) {
  unsigned u = __builtin_bit_cast(unsigned, f);
  u += 0x7FFFu + ((u >> 16) & 1u);
  return (unsigned short)(u >> 16);
}
__device__ __forceinline__ float bf2f(unsigned short h) {
  unsigned u = ((unsigned)h) << 16;
  return __builtin_bit_cast(float, u);
}

__device__ __forceinline__ void gload_lds16(const void* g, void* l) {
  __builtin_amdgcn_global_load_lds(
      (const __attribute__((address_space(1))) void*)g,
      (__attribute__((address_space(3))) void*)l, 16, 0, 0);
}

// ---------------- 256x256 8-phase bf16 GEMM (m201-style template) -----------
// C[m][n] = scale * sum_k A[m][k]*B[n][k] (+ bias[n]). A:[M][K], B:[N][K] bf16.
// Lean registers: acc[8][4] (128 VGPR) + Ar[4][2] (32) + Br0/Br1[2][2] (16+16).
// Stage ledger (per tile t, buf d=t&1): ph1:A0(t+1)->d^1, ph2:A1(t+1)->d^1,
// ph3:B0(t+2)->d, ph4:B1(t+2)->d; vmcnt(4) at ph4 covers all of t+1.
constexpr int BM = 256, BN = 256, BK = 64;

#define BAR() __builtin_amdgcn_s_barrier()
#define LGKM0()                                        \
  do {                                                 \
    asm volatile("s_waitcnt lgkmcnt(0)" ::: "memory"); \
    __builtin_amdgcn_sched_barrier(0);                 \
  } while (0)
#define VMW(N) asm volatile("s_waitcnt vmcnt(" #N ")" ::: "memory")
#define PRIO(x) __builtin_amdgcn_s_setprio(x)

#define MM(a_, b_, c_)                                                        \
  c_ = __builtin_amdgcn_mfma_f32_16x16x32_bf16(                               \
      __builtin_bit_cast(bf16x8, a_), __builtin_bit_cast(bf16x8, b_), c_, 0, 0, 0)

template <int OUT_MODE, bool HAS_BIAS>
__global__ __launch_bounds__(512, 2) void gemm256(
    const unsigned short* __restrict__ A, const unsigned short* __restrict__ B,
    const float* __restrict__ bias, float scale, void* __restrict__ Cv,
    int N, int K, long sA, long sB, long sC, int gx, int gy) {
  __shared__ char sm[131072];  // A: [0,64K): dbuf*32K + half*16K; B: +64K same

  const int nwg = gridDim.x;
  int id = blockIdx.x;
  id = (id & 7) * (nwg >> 3) + (id >> 3);  // XCD swizzle (nwg % 8 == 0)
  const int bx = id % gx;
  const int by = (id / gx) % gy;
  const int bz = id / (gx * gy);

  const int t = threadIdx.x;
  const int lane = t & 63;
  const int w = t >> 6;   // 0..7
  const int wm = w >> 2;  // 0..1
  const int wn = w & 3;   // 0..3

  const int rowBase = by * BM;
  const int colBase = bx * BN;
  const unsigned short* Ab = A + sA * bz;
  const unsigned short* Bb = B + sB * bz;
  const int NT = K >> 6;  // K-tiles of 64 (even, >= 2)

  // staging: half-tile = 128 rows x 64 cols; wave w issue j covers rows
  // [(w+8j)*8,+8); lane l -> row +(l>>3), slot l&7; source chunk inverse-swz.
  const int srl = lane >> 3;
  const int schunk = (lane & 7) ^ srl;

#define STAGE_A(tt, h, d)                                                     \
  do {                                                                        \
    int _kt = (tt); if (_kt > NT - 1) _kt = NT - 1;                           \
    const int _k0 = _kt << 6;                                                 \
    _Pragma("unroll") for (int _j = 0; _j < 2; ++_j) {                        \
      const int _r = (w + 8 * _j) * 8 + srl;                                  \
      gload_lds16(Ab + (size_t)(rowBase + (h) * 128 + _r) * K + _k0 + schunk * 8, \
                  sm + (d) * 32768 + (h) * 16384 + (w + 8 * _j) * 1024);      \
    }                                                                         \
  } while (0)
#define STAGE_B(tt, h, d)                                                     \
  do {                                                                        \
    int _kt = (tt); if (_kt > NT - 1) _kt = NT - 1;                           \
    const int _k0 = _kt << 6;                                                 \
    _Pragma("unroll") for (int _j = 0; _j < 2; ++_j) {                        \
      const int _r = (w + 8 * _j) * 8 + srl;                                  \
      gload_lds16(Bb + (size_t)(colBase + (h) * 128 + _r) * K + _k0 + schunk * 8, \
                  sm + 65536 + (d) * 32768 + (h) * 16384 + (w + 8 * _j) * 1024); \
    }                                                                         \
  } while (0)

  // fragment reads: byte = row_local*128 + (chunk ^ (row&7))*16; row&7 == lr&7.
  const int lr = lane & 15;
  const int g0 = lane >> 4;
  const int sw0 = (g0 ^ (lr & 7)) << 4;
  const int sw1 = ((g0 + 4) ^ (lr & 7)) << 4;
  const int aBase = wm * 16384 + lr * 128;
  const int bBase = 65536 + (wn >> 1) * 16384 + (wn & 1) * 8192 + lr * 128;

  uint4 Ar[4][2], Br0[2][2], Br1[2][2];
  f32x4 acc[8][4];
#pragma unroll
  for (int m = 0; m < 8; ++m)
#pragma unroll
    for (int n = 0; n < 4; ++n) acc[m][n] = (f32x4){0.f, 0.f, 0.f, 0.f};

#define READ_A(d, mh)                                                         \
  do {                                                                        \
    _Pragma("unroll") for (int f = 0; f < 4; ++f) {                           \
      Ar[f][0] = *(const uint4*)(sm + (d) * 32768 + aBase + (mh) * 8192 + f * 2048 + sw0); \
      Ar[f][1] = *(const uint4*)(sm + (d) * 32768 + aBase + (mh) * 8192 + f * 2048 + sw1); \
    }                                                                         \
  } while (0)
#define READ_B0(d)                                                            \
  do {                                                                        \
    _Pragma("unroll") for (int f = 0; f < 2; ++f) {                           \
      Br0[f][0] = *(const uint4*)(sm + (d) * 32768 + bBase + f * 2048 + sw0); \
      Br0[f][1] = *(const uint4*)(sm + (d) * 32768 + bBase + f * 2048 + sw1); \
    }                                                                         \
  } while (0)
#define READ_B1(d)                                                            \
  do {                                                                        \
    _Pragma("unroll") for (int f = 0; f < 2; ++f) {                           \
      Br1[f][0] = *(const uint4*)(sm + (d) * 32768 + bBase + 4096 + f * 2048 + sw0); \
      Br1[f][1] = *(const uint4*)(sm + (d) * 32768 + bBase + 4096 + f * 2048 + sw1); \
    }                                                                         \
  } while (0)

#define MFMA_Q(Bset, mh, nh)                                                  \
  do {                                                                        \
    _Pragma("unroll") for (int kk = 0; kk < 2; ++kk)                          \
        _Pragma("unroll") for (int mf = 0; mf < 4; ++mf)                      \
            _Pragma("unroll") for (int nf = 0; nf < 2; ++nf)                  \
                MM(Ar[mf][kk], Bset[nf][kk], acc[(mh) * 4 + mf][(nh) * 2 + nf]); \
  } while (0)

  // Phases (Gray order m0n0, m0n1, m1n1, m1n0); one half-stage per phase.
#define TILE(t_, d_)                                                          \
  do {                                                                        \
    /* ph1 */ READ_A(d_, 0); READ_B0(d_);                                     \
    STAGE_A((t_) + 1, 0, (d_) ^ 1);                                           \
    BAR(); LGKM0();                                                           \
    PRIO(1); MFMA_Q(Br0, 0, 0); PRIO(0);                                      \
    BAR();                                                                    \
    /* ph2 */ READ_B1(d_);                                                    \
    STAGE_A((t_) + 1, 1, (d_) ^ 1);                                           \
    BAR(); LGKM0();                                                           \
    PRIO(1); MFMA_Q(Br1, 0, 1); PRIO(0);                                      \
    BAR();                                                                    \
    /* ph3 */ READ_A(d_, 1);                                                  \
    STAGE_B((t_) + 2, 0, d_);                                                 \
    BAR(); LGKM0();                                                           \
    PRIO(1); MFMA_Q(Br1, 1, 1); PRIO(0);                                      \
    BAR();                                                                    \
    /* ph4 */ STAGE_B((t_) + 2, 1, d_);                                       \
    VMW(4);                                                                   \
    BAR();                                                                    \
    PRIO(1); MFMA_Q(Br0, 1, 0); PRIO(0);                                      \
    BAR();                                                                    \
  } while (0)

  // prologue: A0(0),A1(0),B0(0),B1(0)->buf0; B0(1),B1(1)->buf1. 12 issues;
  // vmcnt(4) leaves {B0(1),B1(1)} in flight, tile 0 fully landed.
  STAGE_A(0, 0, 0); STAGE_A(0, 1, 0); STAGE_B(0, 0, 0); STAGE_B(0, 1, 0);
  STAGE_B(1, 0, 1); STAGE_B(1, 1, 1);
  VMW(4);
  BAR();

  for (int i = 0; i < (NT >> 1); ++i) {
    TILE(2 * i, 0);
    TILE(2 * i + 1, 1);
  }
  VMW(0);  // drain clamped tail prefetches before teardown

  // Epilogue. D lane mapping: col = lane&15, row = (lane>>4)*4 + r.
#pragma unroll
  for (int n = 0; n < 4; ++n) {
    const int col = colBase + wn * 64 + n * 16 + lr;
    float bvv = 0.f;
    if constexpr (HAS_BIAS) bvv = bias[col];
#pragma unroll
    for (int m = 0; m < 8; ++m) {
      const int row0 = rowBase + wm * 128 + m * 16 + g0 * 4;
      f32x4 v = acc[m][n];
      if constexpr (OUT_MODE == 0) {
        unsigned short* C = (unsigned short*)Cv + sC * bz;
#pragma unroll
        for (int r = 0; r < 4; ++r)
          C[(size_t)(row0 + r) * N + col] = f2bf(v[r] * scale + bvv);
      } else if constexpr (OUT_MODE == 1) {
        unsigned short* C = (unsigned short*)Cv;
        const int b = row0 >> 11, s = row0 & 2047;
        u16x4 pk;
#pragma unroll
        for (int r = 0; r < 4; ++r) pk[r] = f2bf(v[r] * scale + bvv);
        *(u16x4*)&C[((size_t)b * N + col) * 2048 + s] = pk;
      } else {
        float* C = (float*)Cv + sC * bz;
#pragma unroll
        for (int r = 0; r < 4; ++r)
          C[(size_t)(row0 + r) * N + col] = v[r] * scale + bvv;
      }
    }
  }
}

// fp32 -> bf16 (RNE), 8 elems/thread/iter, grid-stride.
__global__ __launch_bounds__(256) void f32_to_bf16(
    const float* __restrict__ in, unsigned short* __restrict__ out, int n8) {
  int i = blockIdx.x * 256 + threadIdx.x;
  const int stride = gridDim.x * 256;
  for (; i < n8; i += stride) {
    float4 a = ((const float4*)in)[2 * i];
    float4 b = ((const float4*)in)[2 * i + 1];
    unsigned short h[8];
    h[0] = f2bf(a.x); h[1] = f2bf(a.y); h[2] = f2bf(a.z); h[3] = f2bf(a.w);
    h[4] = f2bf(b.x); h[5] = f2bf(b.y); h[6] = f2bf(b.z); h[7] = f2bf(b.w);
    ((uint4*)out)[i] = *(uint4*)h;
  }
}

// In-place softmax over rows of 2048 bf16 scores. One block (256 thr) per row.
__global__ __launch_bounds__(256) void softmax_inplace(unsigned short* __restrict__ S) {
  const size_t row = blockIdx.x;
  unsigned short* p = S + row * 2048;
  const int t = threadIdx.x;
  const int lane = t & 63, wid = t >> 6;

  uint4 x = ((const uint4*)p)[t];
  unsigned short* hs = (unsigned short*)&x;
  float f[8];
#pragma unroll
  for (int j = 0; j < 8; ++j) f[j] = bf2f(hs[j]);

  float mx = f[0];
#pragma unroll
  for (int j = 1; j < 8; ++j) mx = fmaxf(mx, f[j]);
#pragma unroll
  for (int d = 1; d < 64; d <<= 1) mx = fmaxf(mx, __shfl_xor(mx, d));
  __shared__ float redm[4];
  if (lane == 0) redm[wid] = mx;
  __syncthreads();
  mx = fmaxf(fmaxf(redm[0], redm[1]), fmaxf(redm[2], redm[3]));

  float e[8], s = 0.f;
#pragma unroll
  for (int j = 0; j < 8; ++j) {
    e[j] = __expf(f[j] - mx);
    s += e[j];
  }
#pragma unroll
  for (int d = 1; d < 64; d <<= 1) s += __shfl_xor(s, d);
  __shared__ float reds[4];
  if (lane == 0) reds[wid] = s;
  __syncthreads();
  s = reds[0] + reds[1] + reds[2] + reds[3];
  const float inv = 1.f / s;

#pragma unroll
  for (int j = 0; j < 8; ++j) hs[j] = f2bf(e[j] * inv);
  ((uint4*)p)[t] = x;
}

extern "C" void kernel_launch(void* const* d_in, const int* in_sizes, int n_in,
                              void* d_out, int out_size, void* d_ws, size_t ws_size,
                              hipStream_t stream) {
  const float* q_embd = (const float*)d_in[0];
  const float* k_embd = (const float*)d_in[1];
  const float* v_embd = (const float*)d_in[2];
  const float* Wq = (const float*)d_in[3];
  const float* bq = (const float*)d_in[4];
  const float* Wk = (const float*)d_in[5];
  const float* bk = (const float*)d_in[6];
  const float* Wv = (const float*)d_in[7];
  const float* bv = (const float*)d_in[8];

  constexpr int B = 8, QL = 2048, KL = 2048, D = 1024;
  constexpr size_t NE = (size_t)B * QL * D;

  unsigned short* qb = (unsigned short*)d_ws;  // [B*QL][D]
  unsigned short* kb = qb + NE;                // [B*KL][D]
  unsigned short* vT = kb + NE;                // [B][D][KL]
  unsigned short* Sb = vT + NE;                // [B][QL][KL] (64 MiB)
  unsigned short* Xe = Sb;                     // conv staging (dead until QK^T)
  unsigned short* Wb = Sb + NE;

  dim3 blk256(256), blk512(512);
  const dim3 gconvE(2048), gconvW(512);
  // proj grid: gx=D/256=4, gy=(B*QL)/256=64 -> 256 blocks
  const dim3 gproj(4 * 64);

  // --- Q projection ---
  f32_to_bf16<<<gconvE, blk256, 0, stream>>>(q_embd, Xe, (int)(NE / 8));
  f32_to_bf16<<<gconvW, blk256, 0, stream>>>(Wq, Wb, D * D / 8);
  gemm256<0, true><<<gproj, blk512, 0, stream>>>(Xe, Wb, bq, 1.0f, qb, D, D,
                                                 0L, 0L, 0L, 4, 64);
  // --- K projection ---
  f32_to_bf16<<<gconvE, blk256, 0, stream>>>(k_embd, Xe, (int)(NE / 8));
  f32_to_bf16<<<gconvW, blk256, 0, stream>>>(Wk, Wb, D * D / 8);
  gemm256<0, true><<<gproj, blk512, 0, stream>>>(Xe, Wb, bk, 1.0f, kb, D, D,
                                                 0L, 0L, 0L, 4, 64);
  // --- V projection (transposed output) ---
  f32_to_bf16<<<gconvE, blk256, 0, stream>>>(v_embd, Xe, (int)(NE / 8));
  f32_to_bf16<<<gconvW, blk256, 0, stream>>>(Wv, Wb, D * D / 8);
  gemm256<1, true><<<gproj, blk512, 0, stream>>>(Xe, Wb, bv, 1.0f, vT, D, D,
                                                 0L, 0L, 0L, 4, 64);

  // --- S = (Q @ K^T)/sqrt(D): gx=8, gy=8, gz=8 -> 512 blocks ---
  gemm256<0, false><<<dim3(512), blk512, 0, stream>>>(
      qb, kb, nullptr, 0.03125f, Sb, KL, D, (long)QL * D, (long)KL * D,
      (long)QL * KL, 8, 8);

  // --- P = softmax(S), in place ---
  softmax_inplace<<<dim3(B * QL), blk256, 0, stream>>>(Sb);

  // --- out = P @ V: gx=4, gy=8, gz=8 -> 256 blocks ---
  gemm256<2, false><<<dim3(256), blk512, 0, stream>>>(
      Sb, vT, nullptr, 1.0f, d_out, D, KL, (long)QL * KL, (long)D * KL,
      (long)QL * D, 4, 8);
}

// Round 6
// 378.146 us; speedup vs baseline: 1.5938x; 1.1056x over previous
//
#include <hip/hip_runtime.h>
#include <hip/hip_bf16.h>

typedef float f32x4 __attribute__((ext_vector_type(4)));
typedef __bf16 bf16x8 __attribute__((ext_vector_type(8)));
typedef unsigned short u16x4 __attribute__((ext_vector_type(4)));

__device__ __forceinline__ unsigned short f2bf(float f) {
  unsigned u = __builtin_bit_cast(unsigned, f);
  u += 0x7FFFu + ((u >> 16) & 1u);
  return (unsigned short)(u >> 16);
}
__device__ __forceinline__ float bf2f(unsigned short h) {
  unsigned u = ((unsigned)h) << 16;
  return __builtin_bit_cast(float, u);
}

__device__ __forceinline__ void gload_lds16(const void* g, void* l) {
  __builtin_amdgcn_global_load_lds(
      (const __attribute__((address_space(1))) void*)g,
      (__attribute__((address_space(3))) void*)l, 16, 0, 0);
}

// ---------------- 256x256 8-phase bf16 GEMM (m201-style template) -----------
// C[m][n] = scale * sum_k A[m][k]*B[n][k] (+ bias[n]). A:[M][K], B:[N][K] bf16.
// HALF-ALIGNED fragment mapping (the round-5 race fix): READ_A(d,mh) reads
// rows mh*128 + wm*64 + f*16 + lr -> entirely within staging half mh, so
//   A-h0 dead after ph1, B-h0 dead after ph1, B-h1 after ph2, A-h1 after ph3.
// Deep-prefetch ledger (tile t, buf d=t&1), race-free by construction:
//   ph2: A0,B0(t+2)->d   ph3: B1(t+2)->d   ph4: A1(t+2)->d, vmcnt(8)
// vmcnt(8) at ph4 = tile t+1's 8 loads landed, t+2's 8 may float (full-tile
// latency cover, ~6 phases from issue to deadline).
constexpr int BM = 256, BN = 256, BK = 64;

#define BAR() __builtin_amdgcn_s_barrier()
#define LGKM0()                                        \
  do {                                                 \
    asm volatile("s_waitcnt lgkmcnt(0)" ::: "memory"); \
    __builtin_amdgcn_sched_barrier(0);                 \
  } while (0)
#define VMW(N) asm volatile("s_waitcnt vmcnt(" #N ")" ::: "memory")
#define PRIO(x) __builtin_amdgcn_s_setprio(x)

#define MM(a_, b_, c_)                                                        \
  c_ = __builtin_amdgcn_mfma_f32_16x16x32_bf16(                               \
      __builtin_bit_cast(bf16x8, a_), __builtin_bit_cast(bf16x8, b_), c_, 0, 0, 0)

template <int OUT_MODE, bool HAS_BIAS>
__global__ __launch_bounds__(512, 2) void gemm256(
    const unsigned short* __restrict__ A, const unsigned short* __restrict__ B,
    const float* __restrict__ bias, float scale, void* __restrict__ Cv,
    int N, int K, long sA, long sB, long sC, int gx, int gy) {
  __shared__ char sm[131072];  // A: [0,64K): dbuf*32K + half*16K; B: +64K same

  const int nwg = gridDim.x;
  int id = blockIdx.x;
  id = (id & 7) * (nwg >> 3) + (id >> 3);  // XCD swizzle (nwg % 8 == 0)
  const int bx = id % gx;
  const int by = (id / gx) % gy;
  const int bz = id / (gx * gy);

  const int t = threadIdx.x;
  const int lane = t & 63;
  const int w = t >> 6;   // 0..7
  const int wm = w >> 2;  // 0..1
  const int wn = w & 3;   // 0..3

  const int rowBase = by * BM;
  const int colBase = bx * BN;
  const unsigned short* Ab = A + sA * bz;
  const unsigned short* Bb = B + sB * bz;
  const int NT = K >> 6;  // K-tiles of 64 (even, >= 2)

  // staging: half-tile = 128 rows x 64 cols; wave w issue j covers rows
  // [(w+8j)*8,+8); lane l -> row +(l>>3), slot l&7; source chunk inverse-swz.
  const int srl = lane >> 3;
  const int schunk = (lane & 7) ^ srl;

#define STAGE_A(tt, h, d)                                                     \
  do {                                                                        \
    int _kt = (tt); if (_kt > NT - 1) _kt = NT - 1;                           \
    const int _k0 = _kt << 6;                                                 \
    _Pragma("unroll") for (int _j = 0; _j < 2; ++_j) {                        \
      const int _r = (w + 8 * _j) * 8 + srl;                                  \
      gload_lds16(Ab + (size_t)(rowBase + (h) * 128 + _r) * K + _k0 + schunk * 8, \
                  sm + (d) * 32768 + (h) * 16384 + (w + 8 * _j) * 1024);      \
    }                                                                         \
  } while (0)
#define STAGE_B(tt, h, d)                                                     \
  do {                                                                        \
    int _kt = (tt); if (_kt > NT - 1) _kt = NT - 1;                           \
    const int _k0 = _kt << 6;                                                 \
    _Pragma("unroll") for (int _j = 0; _j < 2; ++_j) {                        \
      const int _r = (w + 8 * _j) * 8 + srl;                                  \
      gload_lds16(Bb + (size_t)(colBase + (h) * 128 + _r) * K + _k0 + schunk * 8, \
                  sm + 65536 + (d) * 32768 + (h) * 16384 + (w + 8 * _j) * 1024); \
    }                                                                         \
  } while (0)

  // fragment reads (half-aligned): A row = mh*128 + wm*64 + f*16 + lr,
  // B col = nh*128 + wn*32 + f*16 + lr. byte = row*128 + (chunk^(row&7))*16;
  // row&7 == lr&7 (all other terms are multiples of 8+).
  const int lr = lane & 15;
  const int g0 = lane >> 4;
  const int sw0 = (g0 ^ (lr & 7)) << 4;
  const int sw1 = ((g0 + 4) ^ (lr & 7)) << 4;
  const int aBase = wm * 8192 + lr * 128;
  const int bBase = 65536 + wn * 4096 + lr * 128;

  uint4 Ar[4][2], Br0[2][2], Br1[2][2];
  f32x4 acc[8][4];
#pragma unroll
  for (int m = 0; m < 8; ++m)
#pragma unroll
    for (int n = 0; n < 4; ++n) acc[m][n] = (f32x4){0.f, 0.f, 0.f, 0.f};

#define READ_A(d, mh)                                                         \
  do {                                                                        \
    _Pragma("unroll") for (int f = 0; f < 4; ++f) {                           \
      Ar[f][0] = *(const uint4*)(sm + (d) * 32768 + (mh) * 16384 + aBase + f * 2048 + sw0); \
      Ar[f][1] = *(const uint4*)(sm + (d) * 32768 + (mh) * 16384 + aBase + f * 2048 + sw1); \
    }                                                                         \
  } while (0)
#define READ_B0(d)                                                            \
  do {                                                                        \
    _Pragma("unroll") for (int f = 0; f < 2; ++f) {                           \
      Br0[f][0] = *(const uint4*)(sm + (d) * 32768 + bBase + f * 2048 + sw0); \
      Br0[f][1] = *(const uint4*)(sm + (d) * 32768 + bBase + f * 2048 + sw1); \
    }                                                                         \
  } while (0)
#define READ_B1(d)                                                            \
  do {                                                                        \
    _Pragma("unroll") for (int f = 0; f < 2; ++f) {                           \
      Br1[f][0] = *(const uint4*)(sm + (d) * 32768 + 16384 + bBase + f * 2048 + sw0); \
      Br1[f][1] = *(const uint4*)(sm + (d) * 32768 + 16384 + bBase + f * 2048 + sw1); \
    }                                                                         \
  } while (0)

#define MFMA_Q(Bset, mh, nh)                                                  \
  do {                                                                        \
    _Pragma("unroll") for (int kk = 0; kk < 2; ++kk)                          \
        _Pragma("unroll") for (int mf = 0; mf < 4; ++mf)                      \
            _Pragma("unroll") for (int nf = 0; nf < 2; ++nf)                  \
                MM(Ar[mf][kk], Bset[nf][kk], acc[(mh) * 4 + mf][(nh) * 2 + nf]); \
  } while (0)

  // Phases (Gray order m0n0, m0n1, m1n1, m1n0). Each stage targets a region
  // whose only read this tile already retired (reader's lgkmcnt(0) precedes
  // its barrier arrival), and lands before tile t+2 ph1 via vmcnt(8).
#define TILE(t_, d_)                                                          \
  do {                                                                        \
    /* ph1 */ READ_A(d_, 0); READ_B0(d_);                                     \
    BAR(); LGKM0();                                                           \
    PRIO(1); MFMA_Q(Br0, 0, 0); PRIO(0);                                      \
    BAR();                                                                    \
    /* ph2 */ READ_B1(d_);                                                    \
    STAGE_A((t_) + 2, 0, d_); STAGE_B((t_) + 2, 0, d_);                       \
    BAR(); LGKM0();                                                           \
    PRIO(1); MFMA_Q(Br1, 0, 1); PRIO(0);                                      \
    BAR();                                                                    \
    /* ph3 */ READ_A(d_, 1);                                                  \
    STAGE_B((t_) + 2, 1, d_);                                                 \
    BAR(); LGKM0();                                                           \
    PRIO(1); MFMA_Q(Br1, 1, 1); PRIO(0);                                      \
    BAR();                                                                    \
    /* ph4 */ STAGE_A((t_) + 2, 1, d_);                                       \
    VMW(8);                                                                   \
    BAR();                                                                    \
    PRIO(1); MFMA_Q(Br0, 1, 0); PRIO(0);                                      \
    BAR();                                                                    \
  } while (0)

  // prologue: tiles 0 and 1 fully staged (16 loads); vmcnt(8) = tile 0 landed.
  STAGE_A(0, 0, 0); STAGE_B(0, 0, 0); STAGE_B(0, 1, 0); STAGE_A(0, 1, 0);
  STAGE_A(1, 0, 1); STAGE_B(1, 0, 1); STAGE_B(1, 1, 1); STAGE_A(1, 1, 1);
  VMW(8);
  BAR();

  for (int i = 0; i < (NT >> 1); ++i) {
    TILE(2 * i, 0);
    TILE(2 * i + 1, 1);
  }
  VMW(0);  // drain clamped tail prefetches before teardown

  // Epilogue. acc[m][n]: row = (m>>2)*128 + wm*64 + (m&3)*16 + g0*4 + r,
  //                      col = (n>>1)*128 + wn*32 + (n&1)*16 + lr.
#pragma unroll
  for (int n = 0; n < 4; ++n) {
    const int col = colBase + (n >> 1) * 128 + wn * 32 + (n & 1) * 16 + lr;
    float bvv = 0.f;
    if constexpr (HAS_BIAS) bvv = bias[col];
#pragma unroll
    for (int m = 0; m < 8; ++m) {
      const int row0 = rowBase + (m >> 2) * 128 + wm * 64 + (m & 3) * 16 + g0 * 4;
      f32x4 v = acc[m][n];
      if constexpr (OUT_MODE == 0) {
        unsigned short* C = (unsigned short*)Cv + sC * bz;
#pragma unroll
        for (int r = 0; r < 4; ++r)
          C[(size_t)(row0 + r) * N + col] = f2bf(v[r] * scale + bvv);
      } else if constexpr (OUT_MODE == 1) {
        unsigned short* C = (unsigned short*)Cv;
        const int b = row0 >> 11, s = row0 & 2047;
        u16x4 pk;
#pragma unroll
        for (int r = 0; r < 4; ++r) pk[r] = f2bf(v[r] * scale + bvv);
        *(u16x4*)&C[((size_t)b * N + col) * 2048 + s] = pk;
      } else {
        float* C = (float*)Cv + sC * bz;
#pragma unroll
        for (int r = 0; r < 4; ++r)
          C[(size_t)(row0 + r) * N + col] = v[r] * scale + bvv;
      }
    }
  }
}

// fp32 -> bf16 (RNE), 8 elems/thread/iter, grid-stride.
__global__ __launch_bounds__(256) void f32_to_bf16(
    const float* __restrict__ in, unsigned short* __restrict__ out, int n8) {
  int i = blockIdx.x * 256 + threadIdx.x;
  const int stride = gridDim.x * 256;
  for (; i < n8; i += stride) {
    float4 a = ((const float4*)in)[2 * i];
    float4 b = ((const float4*)in)[2 * i + 1];
    unsigned short h[8];
    h[0] = f2bf(a.x); h[1] = f2bf(a.y); h[2] = f2bf(a.z); h[3] = f2bf(a.w);
    h[4] = f2bf(b.x); h[5] = f2bf(b.y); h[6] = f2bf(b.z); h[7] = f2bf(b.w);
    ((uint4*)out)[i] = *(uint4*)h;
  }
}

// In-place softmax over rows of 2048 bf16 scores. One block (256 thr) per row.
__global__ __launch_bounds__(256) void softmax_inplace(unsigned short* __restrict__ S) {
  const size_t row = blockIdx.x;
  unsigned short* p = S + row * 2048;
  const int t = threadIdx.x;
  const int lane = t & 63, wid = t >> 6;

  uint4 x = ((const uint4*)p)[t];
  unsigned short* hs = (unsigned short*)&x;
  float f[8];
#pragma unroll
  for (int j = 0; j < 8; ++j) f[j] = bf2f(hs[j]);

  float mx = f[0];
#pragma unroll
  for (int j = 1; j < 8; ++j) mx = fmaxf(mx, f[j]);
#pragma unroll
  for (int d = 1; d < 64; d <<= 1) mx = fmaxf(mx, __shfl_xor(mx, d));
  __shared__ float redm[4];
  if (lane == 0) redm[wid] = mx;
  __syncthreads();
  mx = fmaxf(fmaxf(redm[0], redm[1]), fmaxf(redm[2], redm[3]));

  float e[8], s = 0.f;
#pragma unroll
  for (int j = 0; j < 8; ++j) {
    e[j] = __expf(f[j] - mx);
    s += e[j];
  }
#pragma unroll
  for (int d = 1; d < 64; d <<= 1) s += __shfl_xor(s, d);
  __shared__ float reds[4];
  if (lane == 0) reds[wid] = s;
  __syncthreads();
  s = reds[0] + reds[1] + reds[2] + reds[3];
  const float inv = 1.f / s;

#pragma unroll
  for (int j = 0; j < 8; ++j) hs[j] = f2bf(e[j] * inv);
  ((uint4*)p)[t] = x;
}

extern "C" void kernel_launch(void* const* d_in, const int* in_sizes, int n_in,
                              void* d_out, int out_size, void* d_ws, size_t ws_size,
                              hipStream_t stream) {
  const float* q_embd = (const float*)d_in[0];
  const float* k_embd = (const float*)d_in[1];
  const float* v_embd = (const float*)d_in[2];
  const float* Wq = (const float*)d_in[3];
  const float* bq = (const float*)d_in[4];
  const float* Wk = (const float*)d_in[5];
  const float* bk = (const float*)d_in[6];
  const float* Wv = (const float*)d_in[7];
  const float* bv = (const float*)d_in[8];

  constexpr int B = 8, QL = 2048, KL = 2048, D = 1024;
  constexpr size_t NE = (size_t)B * QL * D;

  unsigned short* qb = (unsigned short*)d_ws;  // [B*QL][D]
  unsigned short* kb = qb + NE;                // [B*KL][D]
  unsigned short* vT = kb + NE;                // [B][D][KL]
  unsigned short* Sb = vT + NE;                // [B][QL][KL] (64 MiB)
  unsigned short* Xe = Sb;                     // conv staging (dead until QK^T)
  unsigned short* Wb = Sb + NE;

  dim3 blk256(256), blk512(512);
  const dim3 gconvE(2048), gconvW(512);
  // proj grid: gx=D/256=4, gy=(B*QL)/256=64 -> 256 blocks
  const dim3 gproj(4 * 64);

  // --- Q projection ---
  f32_to_bf16<<<gconvE, blk256, 0, stream>>>(q_embd, Xe, (int)(NE / 8));
  f32_to_bf16<<<gconvW, blk256, 0, stream>>>(Wq, Wb, D * D / 8);
  gemm256<0, true><<<gproj, blk512, 0, stream>>>(Xe, Wb, bq, 1.0f, qb, D, D,
                                                 0L, 0L, 0L, 4, 64);
  // --- K projection ---
  f32_to_bf16<<<gconvE, blk256, 0, stream>>>(k_embd, Xe, (int)(NE / 8));
  f32_to_bf16<<<gconvW, blk256, 0, stream>>>(Wk, Wb, D * D / 8);
  gemm256<0, true><<<gproj, blk512, 0, stream>>>(Xe, Wb, bk, 1.0f, kb, D, D,
                                                 0L, 0L, 0L, 4, 64);
  // --- V projection (transposed output) ---
  f32_to_bf16<<<gconvE, blk256, 0, stream>>>(v_embd, Xe, (int)(NE / 8));
  f32_to_bf16<<<gconvW, blk256, 0, stream>>>(Wv, Wb, D * D / 8);
  gemm256<1, true><<<gproj, blk512, 0, stream>>>(Xe, Wb, bv, 1.0f, vT, D, D,
                                                 0L, 0L, 0L, 4, 64);

  // --- S = (Q @ K^T)/sqrt(D): gx=8, gy=8, gz=8 -> 512 blocks ---
  gemm256<0, false><<<dim3(512), blk512, 0, stream>>>(
      qb, kb, nullptr, 0.03125f, Sb, KL, D, (long)QL * D, (long)KL * D,
      (long)QL * KL, 8, 8);

  // --- P = softmax(S), in place ---
  softmax_inplace<<<dim3(B * QL), blk256, 0, stream>>>(Sb);

  // --- out = P @ V: gx=4, gy=8, gz=8 -> 256 blocks ---
  gemm256<2, false><<<dim3(256), blk512, 0, stream>>>(
      Sb, vT, nullptr, 1.0f, d_out, D, KL, (long)QL * KL, (long)D * KL,
      (long)QL * D, 4, 8);
}

// Round 7
// 376.727 us; speedup vs baseline: 1.5998x; 1.0038x over previous
//
#include <hip/hip_runtime.h>
#include <hip/hip_bf16.h>

typedef float f32x4 __attribute__((ext_vector_type(4)));
typedef __bf16 bf16x8 __attribute__((ext_vector_type(8)));
typedef unsigned short u16x4 __attribute__((ext_vector_type(4)));

__device__ __forceinline__ unsigned short f2bf(float f) {
  unsigned u = __builtin_bit_cast(unsigned, f);
  u += 0x7FFFu + ((u >> 16) & 1u);
  return (unsigned short)(u >> 16);
}
__device__ __forceinline__ float bf2f(unsigned short h) {
  unsigned u = ((unsigned)h) << 16;
  return __builtin_bit_cast(float, u);
}

__device__ __forceinline__ void gload_lds16(const void* g, void* l) {
  __builtin_amdgcn_global_load_lds(
      (const __attribute__((address_space(1))) void*)g,
      (__attribute__((address_space(3))) void*)l, 16, 0, 0);
}

// ---------------- 256x256 8-phase bf16 GEMM (m201-style template) -----------
// C[m][n] = scale * sum_k A[m][k]*B[n][k] (+ bias[n]). A:[M][K], B:[N][K] bf16.
// Half-aligned fragment mapping: READ_A(d,mh) reads rows mh*128+wm*64+f*16+lr
// (entirely within staging half mh); A-h0,B-h0 dead after ph1, B-h1 after ph2,
// A-h1 after ph3. Deep-prefetch ledger (tile t, buf d=t&1), race-free:
//   ph2: A0,B0(t+2)->d   ph3: B1(t+2)->d   ph4: A1(t+2)->d, vmcnt(8)
// NO forced lgkmcnt(0) drain: phase-p ds_reads are compiler-visible loads
// consumed by phase-p MFMAs, so the compiler emits fine-grained partial
// lgkmcnt(N) waits interleaved with MFMAs; reads complete before barrier #2
// arrival (their last consuming MFMA precedes it), so next-phase stages into
// the same regions remain write-after-read safe.
constexpr int BM = 256, BN = 256, BK = 64;

#define BAR() __builtin_amdgcn_s_barrier()
#define VMW(N) asm volatile("s_waitcnt vmcnt(" #N ")" ::: "memory")
#define PRIO(x) __builtin_amdgcn_s_setprio(x)

#define MM(a_, b_, c_)                                                        \
  c_ = __builtin_amdgcn_mfma_f32_16x16x32_bf16(                               \
      __builtin_bit_cast(bf16x8, a_), __builtin_bit_cast(bf16x8, b_), c_, 0, 0, 0)

template <int OUT_MODE, bool HAS_BIAS>
__global__ __launch_bounds__(512, 2) void gemm256(
    const unsigned short* __restrict__ A, const unsigned short* __restrict__ B,
    const float* __restrict__ bias, float scale, void* __restrict__ Cv,
    int N, int K, long sA, long sB, long sC, int gx, int gy) {
  __shared__ char sm[131072];  // A: [0,64K): dbuf*32K + half*16K; B: +64K same

  const int nwg = gridDim.x;
  int id = blockIdx.x;
  id = (id & 7) * (nwg >> 3) + (id >> 3);  // XCD swizzle (nwg % 8 == 0)
  const int bx = id % gx;
  const int by = (id / gx) % gy;
  const int bz = id / (gx * gy);

  const int t = threadIdx.x;
  const int lane = t & 63;
  const int w = t >> 6;   // 0..7
  const int wm = w >> 2;  // 0..1
  const int wn = w & 3;   // 0..3

  const int rowBase = by * BM;
  const int colBase = bx * BN;
  const unsigned short* Ab = A + sA * bz;
  const unsigned short* Bb = B + sB * bz;
  const int NT = K >> 6;  // K-tiles of 64 (even, >= 2)

  // staging: half-tile = 128 rows x 64 cols; wave w issue j covers rows
  // [(w+8j)*8,+8); lane l -> row +(l>>3), slot l&7; source chunk inverse-swz.
  const int srl = lane >> 3;
  const int schunk = (lane & 7) ^ srl;

#define STAGE_A(tt, h, d)                                                     \
  do {                                                                        \
    int _kt = (tt); if (_kt > NT - 1) _kt = NT - 1;                           \
    const int _k0 = _kt << 6;                                                 \
    _Pragma("unroll") for (int _j = 0; _j < 2; ++_j) {                        \
      const int _r = (w + 8 * _j) * 8 + srl;                                  \
      gload_lds16(Ab + (size_t)(rowBase + (h) * 128 + _r) * K + _k0 + schunk * 8, \
                  sm + (d) * 32768 + (h) * 16384 + (w + 8 * _j) * 1024);      \
    }                                                                         \
  } while (0)
#define STAGE_B(tt, h, d)                                                     \
  do {                                                                        \
    int _kt = (tt); if (_kt > NT - 1) _kt = NT - 1;                           \
    const int _k0 = _kt << 6;                                                 \
    _Pragma("unroll") for (int _j = 0; _j < 2; ++_j) {                        \
      const int _r = (w + 8 * _j) * 8 + srl;                                  \
      gload_lds16(Bb + (size_t)(colBase + (h) * 128 + _r) * K + _k0 + schunk * 8, \
                  sm + 65536 + (d) * 32768 + (h) * 16384 + (w + 8 * _j) * 1024); \
    }                                                                         \
  } while (0)

  // fragment reads (half-aligned): A row = mh*128 + wm*64 + f*16 + lr,
  // B col = nh*128 + wn*32 + f*16 + lr. byte = row*128 + (chunk^(row&7))*16;
  // row&7 == lr&7 (all other terms are multiples of 8+).
  const int lr = lane & 15;
  const int g0 = lane >> 4;
  const int sw0 = (g0 ^ (lr & 7)) << 4;
  const int sw1 = ((g0 + 4) ^ (lr & 7)) << 4;
  const int aBase = wm * 8192 + lr * 128;
  const int bBase = 65536 + wn * 4096 + lr * 128;

  uint4 Ar[4][2], Br0[2][2], Br1[2][2];
  f32x4 acc[8][4];
#pragma unroll
  for (int m = 0; m < 8; ++m)
#pragma unroll
    for (int n = 0; n < 4; ++n) acc[m][n] = (f32x4){0.f, 0.f, 0.f, 0.f};

#define READ_A(d, mh)                                                         \
  do {                                                                        \
    _Pragma("unroll") for (int f = 0; f < 4; ++f) {                           \
      Ar[f][0] = *(const uint4*)(sm + (d) * 32768 + (mh) * 16384 + aBase + f * 2048 + sw0); \
      Ar[f][1] = *(const uint4*)(sm + (d) * 32768 + (mh) * 16384 + aBase + f * 2048 + sw1); \
    }                                                                         \
  } while (0)
#define READ_B0(d)                                                            \
  do {                                                                        \
    _Pragma("unroll") for (int f = 0; f < 2; ++f) {                           \
      Br0[f][0] = *(const uint4*)(sm + (d) * 32768 + bBase + f * 2048 + sw0); \
      Br0[f][1] = *(const uint4*)(sm + (d) * 32768 + bBase + f * 2048 + sw1); \
    }                                                                         \
  } while (0)
#define READ_B1(d)                                                            \
  do {                                                                        \
    _Pragma("unroll") for (int f = 0; f < 2; ++f) {                           \
      Br1[f][0] = *(const uint4*)(sm + (d) * 32768 + 16384 + bBase + f * 2048 + sw0); \
      Br1[f][1] = *(const uint4*)(sm + (d) * 32768 + 16384 + bBase + f * 2048 + sw1); \
    }                                                                         \
  } while (0)

#define MFMA_Q(Bset, mh, nh)                                                  \
  do {                                                                        \
    _Pragma("unroll") for (int kk = 0; kk < 2; ++kk)                          \
        _Pragma("unroll") for (int mf = 0; mf < 4; ++mf)                      \
            _Pragma("unroll") for (int nf = 0; nf < 2; ++nf)                  \
                MM(Ar[mf][kk], Bset[nf][kk], acc[(mh) * 4 + mf][(nh) * 2 + nf]); \
  } while (0)

  // Phases (Gray order m0n0, m0n1, m1n1, m1n0). B-frag reads issued first so
  // the first MFMA's operands land earliest under partial lgkmcnt waits.
#define TILE(t_, d_)                                                          \
  do {                                                                        \
    /* ph1 */ READ_B0(d_); READ_A(d_, 0);                                     \
    BAR();                                                                    \
    PRIO(1); MFMA_Q(Br0, 0, 0); PRIO(0);                                      \
    BAR();                                                                    \
    /* ph2 */ READ_B1(d_);                                                    \
    STAGE_A((t_) + 2, 0, d_); STAGE_B((t_) + 2, 0, d_);                       \
    BAR();                                                                    \
    PRIO(1); MFMA_Q(Br1, 0, 1); PRIO(0);                                      \
    BAR();                                                                    \
    /* ph3 */ READ_A(d_, 1);                                                  \
    STAGE_B((t_) + 2, 1, d_);                                                 \
    BAR();                                                                    \
    PRIO(1); MFMA_Q(Br1, 1, 1); PRIO(0);                                      \
    BAR();                                                                    \
    /* ph4 */ STAGE_A((t_) + 2, 1, d_);                                       \
    VMW(8);                                                                   \
    BAR();                                                                    \
    PRIO(1); MFMA_Q(Br0, 1, 0); PRIO(0);                                      \
    BAR();                                                                    \
  } while (0)

  // prologue: tiles 0 and 1 fully staged (16 loads); vmcnt(8) = tile 0 landed.
  STAGE_A(0, 0, 0); STAGE_B(0, 0, 0); STAGE_B(0, 1, 0); STAGE_A(0, 1, 0);
  STAGE_A(1, 0, 1); STAGE_B(1, 0, 1); STAGE_B(1, 1, 1); STAGE_A(1, 1, 1);
  VMW(8);
  BAR();

  for (int i = 0; i < (NT >> 1); ++i) {
    TILE(2 * i, 0);
    TILE(2 * i + 1, 1);
  }
  VMW(0);  // drain clamped tail prefetches before teardown

  // Epilogue. acc[m][n]: row = (m>>2)*128 + wm*64 + (m&3)*16 + g0*4 + r,
  //                      col = (n>>1)*128 + wn*32 + (n&1)*16 + lr.
#pragma unroll
  for (int n = 0; n < 4; ++n) {
    const int col = colBase + (n >> 1) * 128 + wn * 32 + (n & 1) * 16 + lr;
    float bvv = 0.f;
    if constexpr (HAS_BIAS) bvv = bias[col];
#pragma unroll
    for (int m = 0; m < 8; ++m) {
      const int row0 = rowBase + (m >> 2) * 128 + wm * 64 + (m & 3) * 16 + g0 * 4;
      f32x4 v = acc[m][n];
      if constexpr (OUT_MODE == 0) {
        unsigned short* C = (unsigned short*)Cv + sC * bz;
#pragma unroll
        for (int r = 0; r < 4; ++r)
          C[(size_t)(row0 + r) * N + col] = f2bf(v[r] * scale + bvv);
      } else if constexpr (OUT_MODE == 1) {
        unsigned short* C = (unsigned short*)Cv;
        const int b = row0 >> 11, s = row0 & 2047;
        u16x4 pk;
#pragma unroll
        for (int r = 0; r < 4; ++r) pk[r] = f2bf(v[r] * scale + bvv);
        *(u16x4*)&C[((size_t)b * N + col) * 2048 + s] = pk;
      } else {
        float* C = (float*)Cv + sC * bz;
#pragma unroll
        for (int r = 0; r < 4; ++r)
          C[(size_t)(row0 + r) * N + col] = v[r] * scale + bvv;
      }
    }
  }
}

// fp32 -> bf16 (RNE), 8 elems/thread/iter, grid-stride.
__global__ __launch_bounds__(256) void f32_to_bf16(
    const float* __restrict__ in, unsigned short* __restrict__ out, int n8) {
  int i = blockIdx.x * 256 + threadIdx.x;
  const int stride = gridDim.x * 256;
  for (; i < n8; i += stride) {
    float4 a = ((const float4*)in)[2 * i];
    float4 b = ((const float4*)in)[2 * i + 1];
    unsigned short h[8];
    h[0] = f2bf(a.x); h[1] = f2bf(a.y); h[2] = f2bf(a.z); h[3] = f2bf(a.w);
    h[4] = f2bf(b.x); h[5] = f2bf(b.y); h[6] = f2bf(b.z); h[7] = f2bf(b.w);
    ((uint4*)out)[i] = *(uint4*)h;
  }
}

// In-place softmax over rows of 2048 bf16 scores. One block (256 thr) per row.
__global__ __launch_bounds__(256) void softmax_inplace(unsigned short* __restrict__ S) {
  const size_t row = blockIdx.x;
  unsigned short* p = S + row * 2048;
  const int t = threadIdx.x;
  const int lane = t & 63, wid = t >> 6;

  uint4 x = ((const uint4*)p)[t];
  unsigned short* hs = (unsigned short*)&x;
  float f[8];
#pragma unroll
  for (int j = 0; j < 8; ++j) f[j] = bf2f(hs[j]);

  float mx = f[0];
#pragma unroll
  for (int j = 1; j < 8; ++j) mx = fmaxf(mx, f[j]);
#pragma unroll
  for (int d = 1; d < 64; d <<= 1) mx = fmaxf(mx, __shfl_xor(mx, d));
  __shared__ float redm[4];
  if (lane == 0) redm[wid] = mx;
  __syncthreads();
  mx = fmaxf(fmaxf(redm[0], redm[1]), fmaxf(redm[2], redm[3]));

  float e[8], s = 0.f;
#pragma unroll
  for (int j = 0; j < 8; ++j) {
    e[j] = __expf(f[j] - mx);
    s += e[j];
  }
#pragma unroll
  for (int d = 1; d < 64; d <<= 1) s += __shfl_xor(s, d);
  __shared__ float reds[4];
  if (lane == 0) reds[wid] = s;
  __syncthreads();
  s = reds[0] + reds[1] + reds[2] + reds[3];
  const float inv = 1.f / s;

#pragma unroll
  for (int j = 0; j < 8; ++j) hs[j] = f2bf(e[j] * inv);
  ((uint4*)p)[t] = x;
}

extern "C" void kernel_launch(void* const* d_in, const int* in_sizes, int n_in,
                              void* d_out, int out_size, void* d_ws, size_t ws_size,
                              hipStream_t stream) {
  const float* q_embd = (const float*)d_in[0];
  const float* k_embd = (const float*)d_in[1];
  const float* v_embd = (const float*)d_in[2];
  const float* Wq = (const float*)d_in[3];
  const float* bq = (const float*)d_in[4];
  const float* Wk = (const float*)d_in[5];
  const float* bk = (const float*)d_in[6];
  const float* Wv = (const float*)d_in[7];
  const float* bv = (const float*)d_in[8];

  constexpr int B = 8, QL = 2048, KL = 2048, D = 1024;
  constexpr size_t NE = (size_t)B * QL * D;

  unsigned short* qb = (unsigned short*)d_ws;  // [B*QL][D]
  unsigned short* kb = qb + NE;                // [B*KL][D]
  unsigned short* vT = kb + NE;                // [B][D][KL]
  unsigned short* Sb = vT + NE;                // [B][QL][KL] (64 MiB)
  unsigned short* Xe = Sb;                     // conv staging (dead until QK^T)
  unsigned short* Wb = Sb + NE;

  dim3 blk256(256), blk512(512);
  const dim3 gconvE(2048), gconvW(512);
  // proj grid: gx=D/256=4, gy=(B*QL)/256=64 -> 256 blocks
  const dim3 gproj(4 * 64);

  // --- Q projection ---
  f32_to_bf16<<<gconvE, blk256, 0, stream>>>(q_embd, Xe, (int)(NE / 8));
  f32_to_bf16<<<gconvW, blk256, 0, stream>>>(Wq, Wb, D * D / 8);
  gemm256<0, true><<<gproj, blk512, 0, stream>>>(Xe, Wb, bq, 1.0f, qb, D, D,
                                                 0L, 0L, 0L, 4, 64);
  // --- K projection ---
  f32_to_bf16<<<gconvE, blk256, 0, stream>>>(k_embd, Xe, (int)(NE / 8));
  f32_to_bf16<<<gconvW, blk256, 0, stream>>>(Wk, Wb, D * D / 8);
  gemm256<0, true><<<gproj, blk512, 0, stream>>>(Xe, Wb, bk, 1.0f, kb, D, D,
                                                 0L, 0L, 0L, 4, 64);
  // --- V projection (transposed output) ---
  f32_to_bf16<<<gconvE, blk256, 0, stream>>>(v_embd, Xe, (int)(NE / 8));
  f32_to_bf16<<<gconvW, blk256, 0, stream>>>(Wv, Wb, D * D / 8);
  gemm256<1, true><<<gproj, blk512, 0, stream>>>(Xe, Wb, bv, 1.0f, vT, D, D,
                                                 0L, 0L, 0L, 4, 64);

  // --- S = (Q @ K^T)/sqrt(D): gx=8, gy=8, gz=8 -> 512 blocks ---
  gemm256<0, false><<<dim3(512), blk512, 0, stream>>>(
      qb, kb, nullptr, 0.03125f, Sb, KL, D, (long)QL * D, (long)KL * D,
      (long)QL * KL, 8, 8);

  // --- P = softmax(S), in place ---
  softmax_inplace<<<dim3(B * QL), blk256, 0, stream>>>(Sb);

  // --- out = P @ V: gx=4, gy=8, gz=8 -> 256 blocks ---
  gemm256<2, false><<<dim3(256), blk512, 0, stream>>>(
      Sb, vT, nullptr, 1.0f, d_out, D, KL, (long)QL * KL, (long)D * KL,
      (long)QL * D, 4, 8);
}

// Round 8
// 371.796 us; speedup vs baseline: 1.6210x; 1.0133x over previous
//
#include <hip/hip_runtime.h>
#include <hip/hip_bf16.h>

typedef float f32x4 __attribute__((ext_vector_type(4)));
typedef __bf16 bf16x8 __attribute__((ext_vector_type(8)));
typedef unsigned short u16x4 __attribute__((ext_vector_type(4)));

__device__ __forceinline__ unsigned short f2bf(float f) {
  unsigned u = __builtin_bit_cast(unsigned, f);
  u += 0x7FFFu + ((u >> 16) & 1u);
  return (unsigned short)(u >> 16);
}
__device__ __forceinline__ float bf2f(unsigned short h) {
  unsigned u = ((unsigned)h) << 16;
  return __builtin_bit_cast(float, u);
}

__device__ __forceinline__ void gload_lds16(const void* g, void* l) {
  __builtin_amdgcn_global_load_lds(
      (const __attribute__((address_space(1))) void*)g,
      (__attribute__((address_space(3))) void*)l, 16, 0, 0);
}

// ------------- 256x256 2-phase-per-K-tile bf16 GEMM (merged phases) ---------
// C[m][n] = scale * sum_k A[m][k]*B[n][k] (+ bias[n]). A:[M][K], B:[N][K] bf16.
// Round-8 change: 4 phases/tile -> 2 phases/tile (32-MFMA bursts) to amortize
// the measured ~1360cyc/phase fixed overhead (phase time was invariant at
// ~1875cyc across rounds 6-7 regardless of content; MfmaUtil 512/1875=27%).
// Ledger (tile t, buf d=t&1):
//  ph-A: read A-h0,B0,B1(d) [16 b128]; stage A-h1(t+1)->d^1  [region last
//        read ph-B(t-1)]; BAR; 32 MFMA (n-quadrants 0,1 of m-half 0); BAR.
//  ph-B: read A-h1(d) [8 b128]; stage A-h0,B-h0,B-h1(t+2)->d [regions last
//        read ph-A(t), 1 barrier back]; BAR; 32 MFMA (m-half 1); VMW(6); BAR.
// vmcnt queue at VMW(6): [A-h1(t+1) x2][A0,B0,B1(t+2) x6] -> waits exactly
// for tile t+1 fully landed; cover = 1-2 phases >= HBM latency.
constexpr int BM = 256, BN = 256, BK = 64;

#define BAR() __builtin_amdgcn_s_barrier()
#define VMW(N) asm volatile("s_waitcnt vmcnt(" #N ")" ::: "memory")
#define PRIO(x) __builtin_amdgcn_s_setprio(x)

#define MM(a_, b_, c_)                                                        \
  c_ = __builtin_amdgcn_mfma_f32_16x16x32_bf16(                               \
      __builtin_bit_cast(bf16x8, a_), __builtin_bit_cast(bf16x8, b_), c_, 0, 0, 0)

template <int OUT_MODE, bool HAS_BIAS>
__global__ __launch_bounds__(512, 2) void gemm256(
    const unsigned short* __restrict__ A, const unsigned short* __restrict__ B,
    const float* __restrict__ bias, float scale, void* __restrict__ Cv,
    int N, int K, long sA, long sB, long sC, int gx, int gy) {
  __shared__ char sm[131072];  // A: [0,64K): dbuf*32K + half*16K; B: +64K same

  const int nwg = gridDim.x;
  int id = blockIdx.x;
  id = (id & 7) * (nwg >> 3) + (id >> 3);  // XCD swizzle (nwg % 8 == 0)
  const int bx = id % gx;
  const int by = (id / gx) % gy;
  const int bz = id / (gx * gy);

  const int t = threadIdx.x;
  const int lane = t & 63;
  const int w = t >> 6;   // 0..7
  const int wm = w >> 2;  // 0..1
  const int wn = w & 3;   // 0..3

  const int rowBase = by * BM;
  const int colBase = bx * BN;
  const unsigned short* Ab = A + sA * bz;
  const unsigned short* Bb = B + sB * bz;
  const int NT = K >> 6;  // K-tiles of 64 (even, >= 2)

  // staging: half-tile = 128 rows x 64 cols; wave w issue j covers rows
  // [(w+8j)*8,+8); lane l -> row +(l>>3), slot l&7; source chunk inverse-swz.
  const int srl = lane >> 3;
  const int schunk = (lane & 7) ^ srl;

#define STAGE_A(tt, h, d)                                                     \
  do {                                                                        \
    int _kt = (tt); if (_kt > NT - 1) _kt = NT - 1;                           \
    const int _k0 = _kt << 6;                                                 \
    _Pragma("unroll") for (int _j = 0; _j < 2; ++_j) {                        \
      const int _r = (w + 8 * _j) * 8 + srl;                                  \
      gload_lds16(Ab + (size_t)(rowBase + (h) * 128 + _r) * K + _k0 + schunk * 8, \
                  sm + (d) * 32768 + (h) * 16384 + (w + 8 * _j) * 1024);      \
    }                                                                         \
  } while (0)
#define STAGE_B(tt, h, d)                                                     \
  do {                                                                        \
    int _kt = (tt); if (_kt > NT - 1) _kt = NT - 1;                           \
    const int _k0 = _kt << 6;                                                 \
    _Pragma("unroll") for (int _j = 0; _j < 2; ++_j) {                        \
      const int _r = (w + 8 * _j) * 8 + srl;                                  \
      gload_lds16(Bb + (size_t)(colBase + (h) * 128 + _r) * K + _k0 + schunk * 8, \
                  sm + 65536 + (d) * 32768 + (h) * 16384 + (w + 8 * _j) * 1024); \
    }                                                                         \
  } while (0)

  // fragment reads (half-aligned): A row = mh*128 + wm*64 + f*16 + lr,
  // B col = nh*128 + wn*32 + f*16 + lr. byte = row*128 + (chunk^(row&7))*16;
  // row&7 == lr&7 (all other terms are multiples of 8+).
  const int lr = lane & 15;
  const int g0 = lane >> 4;
  const int sw0 = (g0 ^ (lr & 7)) << 4;
  const int sw1 = ((g0 + 4) ^ (lr & 7)) << 4;
  const int aBase = wm * 8192 + lr * 128;
  const int bBase = 65536 + wn * 4096 + lr * 128;

  uint4 Ar[4][2], Br0[2][2], Br1[2][2];
  f32x4 acc[8][4];
#pragma unroll
  for (int m = 0; m < 8; ++m)
#pragma unroll
    for (int n = 0; n < 4; ++n) acc[m][n] = (f32x4){0.f, 0.f, 0.f, 0.f};

#define READ_A(d, mh)                                                         \
  do {                                                                        \
    _Pragma("unroll") for (int f = 0; f < 4; ++f) {                           \
      Ar[f][0] = *(const uint4*)(sm + (d) * 32768 + (mh) * 16384 + aBase + f * 2048 + sw0); \
      Ar[f][1] = *(const uint4*)(sm + (d) * 32768 + (mh) * 16384 + aBase + f * 2048 + sw1); \
    }                                                                         \
  } while (0)
#define READ_B0(d)                                                            \
  do {                                                                        \
    _Pragma("unroll") for (int f = 0; f < 2; ++f) {                           \
      Br0[f][0] = *(const uint4*)(sm + (d) * 32768 + bBase + f * 2048 + sw0); \
      Br0[f][1] = *(const uint4*)(sm + (d) * 32768 + bBase + f * 2048 + sw1); \
    }                                                                         \
  } while (0)
#define READ_B1(d)                                                            \
  do {                                                                        \
    _Pragma("unroll") for (int f = 0; f < 2; ++f) {                           \
      Br1[f][0] = *(const uint4*)(sm + (d) * 32768 + 16384 + bBase + f * 2048 + sw0); \
      Br1[f][1] = *(const uint4*)(sm + (d) * 32768 + 16384 + bBase + f * 2048 + sw1); \
    }                                                                         \
  } while (0)

#define MFMA_Q(Bset, mh, nh)                                                  \
  do {                                                                        \
    _Pragma("unroll") for (int kk = 0; kk < 2; ++kk)                          \
        _Pragma("unroll") for (int mf = 0; mf < 4; ++mf)                      \
            _Pragma("unroll") for (int nf = 0; nf < 2; ++nf)                  \
                MM(Ar[mf][kk], Bset[nf][kk], acc[(mh) * 4 + mf][(nh) * 2 + nf]); \
  } while (0)

  // Two phases per K-tile; stages target regions >=1 barrier past their last
  // read (A-h1 of buf d^1 last read at ph-B of the previous tile; A-h0/B-h0/
  // B-h1 of buf d last read at ph-A of this tile).
#define TILE2(t_, d_)                                                         \
  do {                                                                        \
    /* ph-A */ READ_B0(d_); READ_B1(d_); READ_A(d_, 0);                       \
    STAGE_A((t_) + 1, 1, (d_) ^ 1);                                           \
    BAR();                                                                    \
    PRIO(1); MFMA_Q(Br0, 0, 0); MFMA_Q(Br1, 0, 1); PRIO(0);                   \
    BAR();                                                                    \
    /* ph-B */ READ_A(d_, 1);                                                 \
    STAGE_A((t_) + 2, 0, d_); STAGE_B((t_) + 2, 0, d_); STAGE_B((t_) + 2, 1, d_); \
    BAR();                                                                    \
    PRIO(1); MFMA_Q(Br1, 1, 1); MFMA_Q(Br0, 1, 0); PRIO(0);                   \
    VMW(6);                                                                   \
    BAR();                                                                    \
  } while (0)

  // prologue: t0 fully staged (8 loads/wave) + t1's A-h0,B-h0,B-h1 (6);
  // A-h1(t1) is staged at tile0 ph-A. VMW(6) = t0 landed, t1's 6 in flight.
  STAGE_A(0, 0, 0); STAGE_B(0, 0, 0); STAGE_B(0, 1, 0); STAGE_A(0, 1, 0);
  STAGE_A(1, 0, 1); STAGE_B(1, 0, 1); STAGE_B(1, 1, 1);
  VMW(6);
  BAR();

  for (int i = 0; i < (NT >> 1); ++i) {
    TILE2(2 * i, 0);
    TILE2(2 * i + 1, 1);
  }
  VMW(0);  // drain clamped tail prefetches before teardown

  // Epilogue. acc[m][n]: row = (m>>2)*128 + wm*64 + (m&3)*16 + g0*4 + r,
  //                      col = (n>>1)*128 + wn*32 + (n&1)*16 + lr.
#pragma unroll
  for (int n = 0; n < 4; ++n) {
    const int col = colBase + (n >> 1) * 128 + wn * 32 + (n & 1) * 16 + lr;
    float bvv = 0.f;
    if constexpr (HAS_BIAS) bvv = bias[col];
#pragma unroll
    for (int m = 0; m < 8; ++m) {
      const int row0 = rowBase + (m >> 2) * 128 + wm * 64 + (m & 3) * 16 + g0 * 4;
      f32x4 v = acc[m][n];
      if constexpr (OUT_MODE == 0) {
        unsigned short* C = (unsigned short*)Cv + sC * bz;
#pragma unroll
        for (int r = 0; r < 4; ++r)
          C[(size_t)(row0 + r) * N + col] = f2bf(v[r] * scale + bvv);
      } else if constexpr (OUT_MODE == 1) {
        unsigned short* C = (unsigned short*)Cv;
        const int b = row0 >> 11, s = row0 & 2047;
        u16x4 pk;
#pragma unroll
        for (int r = 0; r < 4; ++r) pk[r] = f2bf(v[r] * scale + bvv);
        *(u16x4*)&C[((size_t)b * N + col) * 2048 + s] = pk;
      } else {
        float* C = (float*)Cv + sC * bz;
#pragma unroll
        for (int r = 0; r < 4; ++r)
          C[(size_t)(row0 + r) * N + col] = v[r] * scale + bvv;
      }
    }
  }
}

// fp32 -> bf16 (RNE), 8 elems/thread/iter, grid-stride.
__global__ __launch_bounds__(256) void f32_to_bf16(
    const float* __restrict__ in, unsigned short* __restrict__ out, int n8) {
  int i = blockIdx.x * 256 + threadIdx.x;
  const int stride = gridDim.x * 256;
  for (; i < n8; i += stride) {
    float4 a = ((const float4*)in)[2 * i];
    float4 b = ((const float4*)in)[2 * i + 1];
    unsigned short h[8];
    h[0] = f2bf(a.x); h[1] = f2bf(a.y); h[2] = f2bf(a.z); h[3] = f2bf(a.w);
    h[4] = f2bf(b.x); h[5] = f2bf(b.y); h[6] = f2bf(b.z); h[7] = f2bf(b.w);
    ((uint4*)out)[i] = *(uint4*)h;
  }
}

// In-place softmax over rows of 2048 bf16 scores. One block (256 thr) per row.
__global__ __launch_bounds__(256) void softmax_inplace(unsigned short* __restrict__ S) {
  const size_t row = blockIdx.x;
  unsigned short* p = S + row * 2048;
  const int t = threadIdx.x;
  const int lane = t & 63, wid = t >> 6;

  uint4 x = ((const uint4*)p)[t];
  unsigned short* hs = (unsigned short*)&x;
  float f[8];
#pragma unroll
  for (int j = 0; j < 8; ++j) f[j] = bf2f(hs[j]);

  float mx = f[0];
#pragma unroll
  for (int j = 1; j < 8; ++j) mx = fmaxf(mx, f[j]);
#pragma unroll
  for (int d = 1; d < 64; d <<= 1) mx = fmaxf(mx, __shfl_xor(mx, d));
  __shared__ float redm[4];
  if (lane == 0) redm[wid] = mx;
  __syncthreads();
  mx = fmaxf(fmaxf(redm[0], redm[1]), fmaxf(redm[2], redm[3]));

  float e[8], s = 0.f;
#pragma unroll
  for (int j = 0; j < 8; ++j) {
    e[j] = __expf(f[j] - mx);
    s += e[j];
  }
#pragma unroll
  for (int d = 1; d < 64; d <<= 1) s += __shfl_xor(s, d);
  __shared__ float reds[4];
  if (lane == 0) reds[wid] = s;
  __syncthreads();
  s = reds[0] + reds[1] + reds[2] + reds[3];
  const float inv = 1.f / s;

#pragma unroll
  for (int j = 0; j < 8; ++j) hs[j] = f2bf(e[j] * inv);
  ((uint4*)p)[t] = x;
}

extern "C" void kernel_launch(void* const* d_in, const int* in_sizes, int n_in,
                              void* d_out, int out_size, void* d_ws, size_t ws_size,
                              hipStream_t stream) {
  const float* q_embd = (const float*)d_in[0];
  const float* k_embd = (const float*)d_in[1];
  const float* v_embd = (const float*)d_in[2];
  const float* Wq = (const float*)d_in[3];
  const float* bq = (const float*)d_in[4];
  const float* Wk = (const float*)d_in[5];
  const float* bk = (const float*)d_in[6];
  const float* Wv = (const float*)d_in[7];
  const float* bv = (const float*)d_in[8];

  constexpr int B = 8, QL = 2048, KL = 2048, D = 1024;
  constexpr size_t NE = (size_t)B * QL * D;

  unsigned short* qb = (unsigned short*)d_ws;  // [B*QL][D]
  unsigned short* kb = qb + NE;                // [B*KL][D]
  unsigned short* vT = kb + NE;                // [B][D][KL]
  unsigned short* Sb = vT + NE;                // [B][QL][KL] (64 MiB)
  unsigned short* Xe = Sb;                     // conv staging (dead until QK^T)
  unsigned short* Wb = Sb + NE;

  dim3 blk256(256), blk512(512);
  const dim3 gconvE(2048), gconvW(512);
  // proj grid: gx=D/256=4, gy=(B*QL)/256=64 -> 256 blocks
  const dim3 gproj(4 * 64);

  // --- Q projection ---
  f32_to_bf16<<<gconvE, blk256, 0, stream>>>(q_embd, Xe, (int)(NE / 8));
  f32_to_bf16<<<gconvW, blk256, 0, stream>>>(Wq, Wb, D * D / 8);
  gemm256<0, true><<<gproj, blk512, 0, stream>>>(Xe, Wb, bq, 1.0f, qb, D, D,
                                                 0L, 0L, 0L, 4, 64);
  // --- K projection ---
  f32_to_bf16<<<gconvE, blk256, 0, stream>>>(k_embd, Xe, (int)(NE / 8));
  f32_to_bf16<<<gconvW, blk256, 0, stream>>>(Wk, Wb, D * D / 8);
  gemm256<0, true><<<gproj, blk512, 0, stream>>>(Xe, Wb, bk, 1.0f, kb, D, D,
                                                 0L, 0L, 0L, 4, 64);
  // --- V projection (transposed output) ---
  f32_to_bf16<<<gconvE, blk256, 0, stream>>>(v_embd, Xe, (int)(NE / 8));
  f32_to_bf16<<<gconvW, blk256, 0, stream>>>(Wv, Wb, D * D / 8);
  gemm256<1, true><<<gproj, blk512, 0, stream>>>(Xe, Wb, bv, 1.0f, vT, D, D,
                                                 0L, 0L, 0L, 4, 64);

  // --- S = (Q @ K^T)/sqrt(D): gx=8, gy=8, gz=8 -> 512 blocks ---
  gemm256<0, false><<<dim3(512), blk512, 0, stream>>>(
      qb, kb, nullptr, 0.03125f, Sb, KL, D, (long)QL * D, (long)KL * D,
      (long)QL * KL, 8, 8);

  // --- P = softmax(S), in place ---
  softmax_inplace<<<dim3(B * QL), blk256, 0, stream>>>(Sb);

  // --- out = P @ V: gx=4, gy=8, gz=8 -> 256 blocks ---
  gemm256<2, false><<<dim3(256), blk512, 0, stream>>>(
      Sb, vT, nullptr, 1.0f, d_out, D, KL, (long)QL * KL, (long)D * KL,
      (long)QL * D, 4, 8);
}